// Round 11
// baseline (507.345 us; speedup 1.0000x reference)
//
#include <hip/hip_runtime.h>
#include <hip/hip_bf16.h>
#include <math.h>

#define BATCH 1024
#define LABEL 128
#define LATENT 512
#define NTOT 1152  // 1024 + 128

typedef short short8 __attribute__((ext_vector_type(8)));
typedef float f32x16 __attribute__((ext_vector_type(16)));

__device__ __forceinline__ unsigned short f2bf(float f) {
    __hip_bfloat16 h = __float2bfloat16(f);
    return *(unsigned short*)&h;
}
__device__ __forceinline__ float bf2f(unsigned short u) {
    __hip_bfloat16 h; *(unsigned short*)&h = u;
    return __bfloat162float(h);
}

// conv1 output layout (per image): 3 bf16 planes of 6400 ushorts (12800B each).
// Plane = 196 compact pixels (14x14) x 32ch, granule = 64B, slot-swizzled:
// off = p*32 + (((oc>>3) ^ (p>>1)) & 3)*8 + (oc&7).  Granules 196..199 zeroed
// (conv2's OOB-redirect target).  Image stride = 19200 ushorts.

// ---------------- conv1 (1->32, 5x5 SAME) + relu + 2x2 maxpool ----------------
__global__ __launch_bounds__(256) void conv1_pool(const float* __restrict__ image,
                                                  const float* __restrict__ limg,
                                                  const float* __restrict__ wt,
                                                  const float* __restrict__ bias,
                                                  unsigned short* __restrict__ o1b) {
    const int n = blockIdx.x;
    const float* in = (n < BATCH) ? (image + (size_t)n * 784)
                                  : (limg + (size_t)(n - BATCH) * 784);
    __shared__ float pin[32][32];
    __shared__ float wts[32 * 25];
    const int tid = threadIdx.x;
    unsigned short* ob = o1b + (size_t)n * 19200;
    for (int i = tid; i < 384; i += 256) {            // zero spare granules
        int pl_ = i >> 7, r = i & 127;
        ob[pl_ * 6400 + 6272 + r] = 0;
    }
    for (int idx = tid; idx < 32 * 32; idx += 256) ((float*)pin)[idx] = 0.f;
    __syncthreads();
    for (int idx = tid; idx < 784; idx += 256) {
        int y = idx / 28, x = idx % 28;
        pin[y + 2][x + 2] = in[idx];
    }
    for (int idx = tid; idx < 800; idx += 256) wts[idx] = wt[idx];
    __syncthreads();
    const int oc = tid & 31;
    float wk[25];
    #pragma unroll
    for (int k = 0; k < 25; ++k) wk[k] = wts[oc * 25 + k];
    float b = bias[oc];
    const int slot_lo = (oc & 7);
    const int gq = oc >> 3;
    for (int o = tid; o < 6272; o += 256) {
        int p = o >> 5, py = p / 14, px = p % 14;
        float win[6][6];
        #pragma unroll
        for (int r = 0; r < 6; ++r)
        #pragma unroll
        for (int c = 0; c < 6; ++c)
            win[r][c] = pin[2 * py + r][2 * px + c];
        float a00 = b, a01 = b, a10 = b, a11 = b;
        #pragma unroll
        for (int ky = 0; ky < 5; ++ky)
        #pragma unroll
        for (int kx = 0; kx < 5; ++kx) {
            float w = wk[ky * 5 + kx];
            a00 = fmaf(win[ky][kx], w, a00);
            a01 = fmaf(win[ky][kx + 1], w, a01);
            a10 = fmaf(win[ky + 1][kx], w, a10);
            a11 = fmaf(win[ky + 1][kx + 1], w, a11);
        }
        float v = fmaxf(fmaxf(fmaxf(a00, a01), fmaxf(a10, a11)), 0.f);
        unsigned short b1 = f2bf(v); float r1 = v - bf2f(b1);
        unsigned short b2 = f2bf(r1);
        unsigned short b3 = f2bf(r1 - bf2f(b2));
        int off = p * 32 + (((gq ^ (p >> 1)) & 3) << 3) + slot_lo;
        ob[off] = b1; ob[6400 + off] = b2; ob[12800 + off] = b3;
    }
}

// ---------------- B fragment prep for conv2 (unchanged, r7 proven) ------------
__global__ __launch_bounds__(256) void bprep(const float* __restrict__ w,
                                             unsigned short* __restrict__ Bf) {
    int idx = blockIdx.x * 256 + threadIdx.x;   // 50*2*64*8 = 51200
    if (idx >= 51200) return;
    int j = idx & 7, lane = (idx >> 3) & 63, ocT = (idx >> 9) & 1, s = idx >> 10;
    int q = lane >> 5, nn = lane & 31;
    int k = 16 * s + 8 * q + j;
    int tap = k >> 5, ic = k & 31;
    int oc = 32 * ocT + nn;
    float v = w[oc * 800 + ic * 25 + tap];
    unsigned short b1 = f2bf(v);
    float r1 = v - bf2f(b1);
    unsigned short b2 = f2bf(r1);
    unsigned short b3 = f2bf(r1 - bf2f(b2));
    size_t base = ((size_t)(s * 2 + ocT) * 3) * 512 + lane * 8 + j;
    Bf[base] = b1; Bf[base + 512] = b2; Bf[base + 1024] = b3;
}

// ---------------- f1w prep: bf16x3 planes Bw3[pl][512][3136] ------------------
#define BSTR ((size_t)512 * 3136)
#define ASTR ((size_t)NTOT * 3136)
__global__ __launch_bounds__(256) void wprep(const float* __restrict__ w,
                                             unsigned short* __restrict__ B3) {
    int idx = blockIdx.x * 256 + threadIdx.x;   // 512*3136
    if (idx >= 512 * 3136) return;
    float v = w[idx];
    unsigned short b1 = f2bf(v);
    float r1 = v - bf2f(b1);
    unsigned short b2 = f2bf(r1);
    unsigned short b3 = f2bf(r1 - bf2f(b2));
    B3[idx] = b1; B3[BSTR + idx] = b2; B3[2 * BSTR + idx] = b3;
}

// ---------------- conv2 via MFMA (bf16x3), v5: 8 waves, no K-split ------------
// r10 showed conv2 latency-bound: acc[7] = 112 AGPR + 124 VGPR -> 2 waves/SIMD.
// v5: 512 thr = 8 waves = (ocT, mq); each wave owns <=2 M-tiles over FULL K.
// acc drops to 32 AGPR/thread -> ~4 waves/SIMD; 2 blocks/CU -> 16 waves/CU.
// K-merge phases deleted. mq=3's dead tile (t=7) reads the zeroed granule.
__global__ __launch_bounds__(512) void conv2_mfma(const unsigned short* __restrict__ o1b,
                                                  const unsigned short* __restrict__ Bf,
                                                  const float* __restrict__ bias,
                                                  unsigned short* __restrict__ out3) {
    const int n = blockIdx.x;
    __shared__ __align__(16) unsigned short pl[19200];   // 38,400B
    const int tid = threadIdx.x;
    const int lane = tid & 63, wv = tid >> 6;
    const int ocT = wv & 1, mq = wv >> 1;

    // ---- stage: linear copy (planes already split + swizzled by conv1) ----
    {
        const float4* src = (const float4*)(o1b + (size_t)n * 19200);
        float4* dst = (float4*)pl;
        for (int i = tid; i < 2400; i += 512) dst[i] = src[i];
    }
    __syncthreads();

    const int m_ = lane & 31, q = lane >> 5;
    int ym[2], xm[2], mm[2], tv[2];
    #pragma unroll
    for (int tt = 0; tt < 2; ++tt) {
        int t = 2 * mq + tt;
        tv[tt] = (t < 7);
        int m = 32 * t + m_;
        mm[tt] = m;
        int y = tv[tt] ? (m / 14) : 13;
        if (y > 13) y = 13;
        ym[tt] = y;
        xm[tt] = m - 14 * y;
    }
    f32x16 acc[2];
    {
        float bs = bias[32 * ocT + m_];
        #pragma unroll
        for (int tt = 0; tt < 2; ++tt)
        #pragma unroll
        for (int r = 0; r < 16; ++r) acc[tt][r] = bs;
    }

    for (int s = 0; s < 50; ++s) {
        const unsigned short* bp = Bf + ((size_t)(s * 2 + ocT) * 3) * 512 + lane * 8;
        short8 b1 = *(const short8*)(bp);
        short8 b2 = *(const short8*)(bp + 512);
        short8 b3 = *(const short8*)(bp + 1024);
        int kb = 16 * s + 8 * q;
        int tap = kb >> 5, ic0 = kb & 31, g = ic0 >> 3;
        int ky = (tap * 13) >> 6;       // exact /5 for tap<25
        int kx = tap - ky * 5;
        int iyk = ky - 2, ixk = kx - 2;
        int pq2 = iyk * 14 + ixk;
        short8 a1[2], a2[2], a3[2];
        #pragma unroll
        for (int tt = 0; tt < 2; ++tt) {
            int iy = ym[tt] + iyk, ix = xm[tt] + ixk;
            int valid = tv[tt] & ((unsigned)iy < 14u) & ((unsigned)ix < 14u);
            int cpt = valid ? (mm[tt] + pq2) : 196;
            int addr = cpt * 32 + (((g ^ (cpt >> 1)) & 3) << 3);
            a1[tt] = *(const short8*)(pl + addr);
            a2[tt] = *(const short8*)(pl + 6400 + addr);
            a3[tt] = *(const short8*)(pl + 12800 + addr);
        }
        #pragma unroll
        for (int tt = 0; tt < 2; ++tt)
            acc[tt] = __builtin_amdgcn_mfma_f32_32x32x16_bf16(a1[tt], b1, acc[tt], 0, 0, 0);
        #pragma unroll
        for (int tt = 0; tt < 2; ++tt)
            acc[tt] = __builtin_amdgcn_mfma_f32_32x32x16_bf16(a1[tt], b2, acc[tt], 0, 0, 0);
        #pragma unroll
        for (int tt = 0; tt < 2; ++tt)
            acc[tt] = __builtin_amdgcn_mfma_f32_32x32x16_bf16(a2[tt], b1, acc[tt], 0, 0, 0);
        #pragma unroll
        for (int tt = 0; tt < 2; ++tt)
            acc[tt] = __builtin_amdgcn_mfma_f32_32x32x16_bf16(a2[tt], b2, acc[tt], 0, 0, 0);
        #pragma unroll
        for (int tt = 0; tt < 2; ++tt)
            acc[tt] = __builtin_amdgcn_mfma_f32_32x32x16_bf16(a1[tt], b3, acc[tt], 0, 0, 0);
        #pragma unroll
        for (int tt = 0; tt < 2; ++tt)
            acc[tt] = __builtin_amdgcn_mfma_f32_32x32x16_bf16(a3[tt], b1, acc[tt], 0, 0, 0);
    }
    __syncthreads();   // planes dead

    // ---- x-pool in-lane -> hx[y][px][oc], stride 65 ----
    float* hx = (float*)pl;        // 25.5KB, aliases planes (post-sync)
    {
        const int oc = 32 * ocT + m_;
        #pragma unroll
        for (int tt = 0; tt < 2; ++tt)
        #pragma unroll
        for (int e = 0; e < 8; ++e) {
            const int reg = 2 * e;
            const int r = (reg & 3) + 8 * (reg >> 2) + 4 * q;
            const int m = 32 * (2 * mq + tt) + r;
            if (m < 196) {
                float xm2 = fmaxf(acc[tt][reg], acc[tt][reg + 1]);
                int y = (m * 2341) >> 15;        // /14
                int px = (m - 14 * y) >> 1;
                hx[(y * 7 + px) * 65 + oc] = xm2;
            }
        }
    }
    __syncthreads();

    // ---- y-pool + relu + bf16x3 store ----
    const size_t OSTR = ASTR;
    for (int idx = tid; idx < 3136; idx += 512) {
        int oc2 = (idx * 2675) >> 17;        // /49
        int p = idx - 49 * oc2;
        int py = (p * 9363) >> 16;           // /7
        int px = p - 7 * py;
        float v = fmaxf(hx[(2 * py * 7 + px) * 65 + oc2],
                        hx[((2 * py + 1) * 7 + px) * 65 + oc2]);
        v = fmaxf(v, 0.f);
        unsigned short b1 = f2bf(v);
        float r1 = v - bf2f(b1);
        unsigned short b2 = f2bf(r1);
        unsigned short b3 = f2bf(r1 - bf2f(b2));
        size_t o = (size_t)n * 3136 + idx;
        out3[o] = b1; out3[OSTR + o] = b2; out3[2 * OSTR + o] = b3;
    }
}

// ---------------- fc1 via MFMA (bf16x3, 6 products), split-K=7 ----------------
__global__ __launch_bounds__(256) void fc1_mfma(const unsigned short* __restrict__ A3,
                                                const unsigned short* __restrict__ B3,
                                                float* __restrict__ part) {
    __shared__ unsigned short As[3][2048];
    __shared__ unsigned short Bs[3][2048];
    const int tid = threadIdx.x;
    const int n0 = blockIdx.x * 64, m0 = blockIdx.y * 64;
    const int koff = blockIdx.z * 448;
    const int lr = tid >> 2, g = tid & 3;
    const int slot = (((g ^ (lr >> 1)) & 3) << 3);
    const int lane = tid & 63, wv = tid >> 6;
    const int nq = wv & 1, mq = wv >> 1;
    const int q = lane >> 5, l31 = lane & 31;
    const int rA = 32 * nq + l31, rB = 32 * mq + l31;
    f32x16 acc;
    #pragma unroll
    for (int r = 0; r < 16; ++r) acc[r] = 0.f;

    for (int bk = 0; bk < 448; bk += 32) {
        const size_t ka = (size_t)(koff + bk + (g << 3));
        short8 av[3], bv[3];
        #pragma unroll
        for (int p = 0; p < 3; ++p) {
            av[p] = *(const short8*)(A3 + p * ASTR + (size_t)(n0 + lr) * 3136 + ka);
            bv[p] = *(const short8*)(B3 + p * BSTR + (size_t)(m0 + lr) * 3136 + ka);
        }
        __syncthreads();
        #pragma unroll
        for (int p = 0; p < 3; ++p) {
            *(short8*)&As[p][(lr << 5) + slot] = av[p];
            *(short8*)&Bs[p][(lr << 5) + slot] = bv[p];
        }
        __syncthreads();
        #pragma unroll
        for (int s2 = 0; s2 < 32; s2 += 16) {
            const int gg = (s2 + (q << 3)) >> 3;
            const int sa = (((gg ^ (rA >> 1)) & 3) << 3);
            const int sb = (((gg ^ (rB >> 1)) & 3) << 3);
            short8 a1 = *(const short8*)&As[0][(rA << 5) + sa];
            short8 a2 = *(const short8*)&As[1][(rA << 5) + sa];
            short8 a3 = *(const short8*)&As[2][(rA << 5) + sa];
            short8 b1 = *(const short8*)&Bs[0][(rB << 5) + sb];
            short8 b2 = *(const short8*)&Bs[1][(rB << 5) + sb];
            short8 b3 = *(const short8*)&Bs[2][(rB << 5) + sb];
            acc = __builtin_amdgcn_mfma_f32_32x32x16_bf16(a1, b1, acc, 0, 0, 0);
            acc = __builtin_amdgcn_mfma_f32_32x32x16_bf16(a1, b2, acc, 0, 0, 0);
            acc = __builtin_amdgcn_mfma_f32_32x32x16_bf16(a2, b1, acc, 0, 0, 0);
            acc = __builtin_amdgcn_mfma_f32_32x32x16_bf16(a2, b2, acc, 0, 0, 0);
            acc = __builtin_amdgcn_mfma_f32_32x32x16_bf16(a1, b3, acc, 0, 0, 0);
            acc = __builtin_amdgcn_mfma_f32_32x32x16_bf16(a3, b1, acc, 0, 0, 0);
        }
    }
    float* pb = part + (size_t)blockIdx.z * NTOT * 512;
    #pragma unroll
    for (int reg = 0; reg < 16; ++reg) {
        int nn = n0 + 32 * nq + (reg & 3) + 8 * (reg >> 2) + 4 * q;
        int mmo = m0 + 32 * mq + l31;
        pb[(size_t)nn * 512 + mmo] = acc[reg];
    }
}

__global__ __launch_bounds__(256) void fc1_reduce(const float* __restrict__ part,
                                                  const float* __restrict__ bias,
                                                  float* __restrict__ lat,
                                                  float* __restrict__ rep) {
    int idx = blockIdx.x * 256 + threadIdx.x;
    int m = idx & 511;
    float v = bias[m];
    #pragma unroll
    for (int kz = 0; kz < 7; ++kz) v += part[(size_t)kz * NTOT * 512 + idx];
    if (idx < BATCH * 512) lat[idx] = v;
    else rep[idx - BATCH * 512] = tanhf(v);
}

// ---------------- label = softmax(lat @ fcn_w.T + fcn_b) ----------------
__global__ __launch_bounds__(128) void fcn_softmax(const float* __restrict__ lat,
                                                   const float* __restrict__ fw,
                                                   const float* __restrict__ fb,
                                                   float* __restrict__ out) {
    const int b = blockIdx.x;
    const int j = threadIdx.x;
    __shared__ float lrow[512];
    __shared__ float red[128];
    for (int i = j; i < 512; i += 128) lrow[i] = lat[b * 512 + i];
    __syncthreads();
    const float4* w4 = (const float4*)(fw + j * 512);
    float acc = fb[j];
    #pragma unroll 4
    for (int qq = 0; qq < 128; ++qq) {
        float4 a = ((const float4*)lrow)[qq];
        float4 w = w4[qq];
        acc += a.x * w.x + a.y * w.y + a.z * w.z + a.w * w.w;
    }
    red[j] = acc;
    __syncthreads();
    for (int off = 64; off >= 1; off >>= 1) {
        if (j < off) red[j] = fmaxf(red[j], red[j + off]);
        __syncthreads();
    }
    float mx = red[0];
    __syncthreads();
    float ex = expf(acc - mx);
    red[j] = ex;
    __syncthreads();
    for (int off = 64; off >= 1; off >>= 1) {
        if (j < off) red[j] += red[j + off];
        __syncthreads();
    }
    out[b * 128 + j] = ex / red[0];
}

// ---------------- rho / t / w ----------------
__global__ __launch_bounds__(256) void rho_kernel(const float* __restrict__ rep,
                                                  float* __restrict__ rho) {
    __shared__ float red[256];
    const int tid = threadIdx.x;
    float s = 0.f;
    for (int i = tid; i < LABEL * LATENT; i += 256) s += rep[i];
    red[tid] = s;
    __syncthreads();
    for (int off = 128; off >= 1; off >>= 1) {
        if (tid < off) red[tid] += red[tid + off];
        __syncthreads();
    }
    if (tid == 0) rho[0] = red[0] / (float)(LABEL * LATENT);
}

__global__ __launch_bounds__(256) void t_kernel(const float* __restrict__ rep,
                                                const float* __restrict__ rho,
                                                float* __restrict__ tT) {
    int idx = blockIdx.x * 256 + threadIdx.x;
    int i = idx / 128, k = idx % 128;
    tT[idx] = rep[k * 512 + i] - rho[0];
}

__global__ __launch_bounds__(256) void w_kernel(const float* __restrict__ tT,
                                                float* __restrict__ w) {
    int idx = blockIdx.x * 256 + threadIdx.x;
    int i = idx >> 9, j = idx & 511;
    const float4* a = (const float4*)(tT + i * 128);
    const float4* b = (const float4*)(tT + j * 128);
    float acc = 0.f;
    #pragma unroll 8
    for (int q = 0; q < 32; ++q) {
        float4 av = a[q], bv = b[q];
        acc += av.x * bv.x + av.y * bv.y + av.z * bv.z + av.w * bv.w;
    }
    w[idx] = (i == j) ? 0.f : acc * (1.f / 128.f);
}

// ---------------- clustering (r6 proven): incremental Hopfield ----------------
#define CB 4
__device__ __forceinline__ float sgnf(float x) {
    return (x > 0.f) ? 1.f : ((x < 0.f) ? -1.f : 0.f);
}

__global__ __launch_bounds__(256) void clustering(const float* __restrict__ lat,
                                                  const float* __restrict__ w,
                                                  const float* __restrict__ rep,
                                                  float* __restrict__ out) {
    const int tid = threadIdx.x;
    const int row0 = blockIdx.x * CB;
    __shared__ float sbuf[CB][512];
    __shared__ float mins[CB][512];
    __shared__ float red[256];
    __shared__ float part_e[4][CB];
    __shared__ int part_c[4];
    __shared__ float min_e[CB];
    __shared__ int copyf[CB];
    __shared__ int donef[CB];
    __shared__ int cnt[CB];
    __shared__ int jidx[CB][512];
    __shared__ float jdel[CB][512];
    const int i0 = 2 * tid, i1 = 2 * tid + 1;
    const int wave = tid >> 6, lane = tid & 63;

    float sm10[CB], sm11[CB], sm20[CB], sm21[CB], h0[CB], h1[CB];
    #pragma unroll
    for (int r = 0; r < CB; ++r) {
        float a = tanhf(lat[(row0 + r) * 512 + i0]);
        float b = tanhf(lat[(row0 + r) * 512 + i1]);
        sm10[r] = a; sm11[r] = b;
        sm20[r] = a; sm21[r] = b;
        sbuf[r][i0] = a; sbuf[r][i1] = b;
        h0[r] = 0.f; h1[r] = 0.f;
    }
    if (tid < CB) { min_e[tid] = INFINITY; donef[tid] = 0; cnt[tid] = 0; }
    __syncthreads();

    #pragma unroll 4
    for (int j = 0; j < 512; ++j) {
        float2 wvv = *(const float2*)(w + (size_t)j * 512 + i0);
        #pragma unroll
        for (int r = 0; r < CB; ++r) {
            float sj = sbuf[r][j];
            h0[r] = fmaf(sj, wvv.x, h0[r]);
            h1[r] = fmaf(sj, wvv.y, h1[r]);
        }
    }

    for (int k = 1; k <= 512; ++k) {
        float sn0[CB], sn1[CB];
        int cy = 0xF;
        #pragma unroll
        for (int r = 0; r < CB; ++r) {
            int dn = donef[r];
            if (dn) {
                sn0[r] = sm10[r]; sn1[r] = sm11[r];
            } else {
                sn0[r] = fabsf(sm10[r]) * sgnf(h0[r]);
                sn1[r] = fabsf(sm11[r]) * sgnf(h1[r]);
                if (!(sn0[r] == sm20[r] && sn1[r] == sm21[r])) cy &= ~(1 << r);
                if (sn0[r] != sm10[r]) {
                    int p = atomicAdd(&cnt[r], 1);
                    jidx[r][p] = i0; jdel[r][p] = sn0[r] - sm10[r];
                }
                if (sn1[r] != sm11[r]) {
                    int p = atomicAdd(&cnt[r], 1);
                    jidx[r][p] = i1; jdel[r][p] = sn1[r] - sm11[r];
                }
            }
        }
        #pragma unroll
        for (int m = 32; m >= 1; m >>= 1) cy &= __shfl_xor(cy, m, 64);
        if (lane == 0) part_c[wave] = cy;
        __syncthreads();

        #pragma unroll
        for (int r = 0; r < CB; ++r) {
            const int c = cnt[r];
            for (int t = 0; t < c; ++t) {
                const int j = jidx[r][t];
                const float d = jdel[r][t];
                const float2 wvv = *(const float2*)(w + (size_t)j * 512 + i0);
                h0[r] = fmaf(d, wvv.x, h0[r]);
                h1[r] = fmaf(d, wvv.y, h1[r]);
            }
        }
        float ep[CB];
        #pragma unroll
        for (int r = 0; r < CB; ++r) ep[r] = sn0[r] * h0[r] + sn1[r] * h1[r];
        #pragma unroll
        for (int m = 32; m >= 1; m >>= 1) {
            #pragma unroll
            for (int r = 0; r < CB; ++r) ep[r] += __shfl_xor(ep[r], m, 64);
        }
        if (lane == 0) {
            #pragma unroll
            for (int r = 0; r < CB; ++r) part_e[wave][r] = ep[r];
        }
        __syncthreads();

        if (tid < CB) {
            int r = tid;
            if (!donef[r]) {
                float e = -(part_e[0][r] + part_e[1][r] + part_e[2][r] + part_e[3][r]);
                int better = e < min_e[r];
                if (better) min_e[r] = e;
                copyf[r] = better;
                int fl = part_c[0] & part_c[1] & part_c[2] & part_c[3];
                int fixedp = (cnt[r] == 0);
                int cyc = (k >= 2) && ((fl >> r) & 1);
                if (fixedp || cyc) donef[r] = 1;
            } else {
                copyf[r] = 0;
            }
            cnt[r] = 0;
        }
        __syncthreads();

        int alldone = 1;
        #pragma unroll
        for (int r = 0; r < CB; ++r) {
            if (copyf[r]) { mins[r][i0] = sn0[r]; mins[r][i1] = sn1[r]; }
            alldone &= donef[r];
            sm20[r] = sm10[r]; sm21[r] = sm11[r];
            sm10[r] = sn0[r];  sm11[r] = sn1[r];
        }
        if (alldone) break;
    }
    __syncthreads();

    const int j = tid & 127, half = tid >> 7;
    for (int r = 0; r < CB; ++r) {
        const float4* rr = (const float4*)(rep + (size_t)j * 512 + half * 256);
        const float4* ms = (const float4*)(&mins[r][half * 256]);
        float p = 0.f;
        #pragma unroll 8
        for (int q = 0; q < 64; ++q) {
            float4 rv = rr[q], mv = ms[q];
            p += rv.x * mv.x + rv.y * mv.y + rv.z * mv.z + rv.w * mv.w;
        }
        red[tid] = p;
        __syncthreads();
        float v = 0.f;
        if (tid < 128) { v = fabsf(red[tid] + red[tid + 128]); red[tid] = v; }
        __syncthreads();
        for (int off = 64; off >= 1; off >>= 1) {
            if (tid < off) red[tid] = fmaxf(red[tid], red[tid + off]);
            __syncthreads();
        }
        float mx = red[0];
        __syncthreads();
        float ex = 0.f;
        if (tid < 128) { ex = expf(v - mx); red[tid] = ex; }
        __syncthreads();
        for (int off = 64; off >= 1; off >>= 1) {
            if (tid < off) red[tid] += red[tid + off];
            __syncthreads();
        }
        if (tid < 128) out[(size_t)(row0 + r) * 128 + tid] = ex / red[0];
        __syncthreads();
    }
}

extern "C" void kernel_launch(void* const* d_in, const int* in_sizes, int n_in,
                              void* d_out, int out_size, void* d_ws, size_t ws_size,
                              hipStream_t stream) {
    const float* image = (const float*)d_in[0];
    const float* limg  = (const float*)d_in[1];
    const float* c1w   = (const float*)d_in[2];
    const float* c1b   = (const float*)d_in[3];
    const float* c2w   = (const float*)d_in[4];
    const float* c2b   = (const float*)d_in[5];
    const float* f1w   = (const float*)d_in[6];
    const float* f1b   = (const float*)d_in[7];
    const float* fnw   = (const float*)d_in[8];
    const float* fnb   = (const float*)d_in[9];
    float* out = (float*)d_out;
    float* ws  = (float*)d_ws;

    unsigned short* o1b  = (unsigned short*)ws;        // 1152*19200 us = 44.2MB
    unsigned short* out3 = o1b + (size_t)NTOT * 19200; // 3*ASTR bf16
    float* lat  = (float*)(out3 + 3 * ASTR);           // 1024*512
    float* rep  = lat + (size_t)BATCH * 512;           // 128*512
    float* tT   = rep + (size_t)LABEL * 512;           // 512*128
    float* wmat = tT + (size_t)512 * 128;              // 512*512
    float* rho  = wmat + (size_t)512 * 512;            // 1 (+pad)
    unsigned short* Bw3   = (unsigned short*)(rho + 16);   // 3*BSTR bf16
    unsigned short* Bfrag = Bw3 + 3 * BSTR;                // 153,600 bf16
    float* part = (float*)ws;                          // alias o1b (dead after conv2)

    hipLaunchKernelGGL(bprep, dim3(200), dim3(256), 0, stream, c2w, Bfrag);
    hipLaunchKernelGGL(wprep, dim3(6272), dim3(256), 0, stream, f1w, Bw3);
    hipLaunchKernelGGL(conv1_pool, dim3(NTOT), dim3(256), 0, stream, image, limg, c1w, c1b, o1b);
    hipLaunchKernelGGL(conv2_mfma, dim3(NTOT), dim3(512), 0, stream, o1b, Bfrag, c2b, out3);
    hipLaunchKernelGGL(fc1_mfma, dim3(NTOT / 64, 512 / 64, 7), dim3(256), 0, stream,
                       out3, Bw3, part);
    hipLaunchKernelGGL(fc1_reduce, dim3(NTOT * 512 / 256), dim3(256), 0, stream,
                       part, f1b, lat, rep);
    hipLaunchKernelGGL(fcn_softmax, dim3(BATCH), dim3(128), 0, stream, lat, fnw, fnb,
                       out + (size_t)BATCH * LABEL);
    hipLaunchKernelGGL(rho_kernel, dim3(1), dim3(256), 0, stream, rep, rho);
    hipLaunchKernelGGL(t_kernel, dim3(256), dim3(256), 0, stream, rep, rho, tT);
    hipLaunchKernelGGL(w_kernel, dim3(1024), dim3(256), 0, stream, tT, wmat);
    hipLaunchKernelGGL(clustering, dim3(BATCH / CB), dim3(256), 0, stream, lat, wmat, rep, out);
}

// Round 12
// 446.706 us; speedup vs baseline: 1.1357x; 1.1357x over previous
//
#include <hip/hip_runtime.h>
#include <hip/hip_bf16.h>
#include <math.h>

#define BATCH 1024
#define LABEL 128
#define LATENT 512
#define NTOT 1152  // 1024 + 128

typedef short short8 __attribute__((ext_vector_type(8)));
typedef float f32x16 __attribute__((ext_vector_type(16)));

__device__ __forceinline__ unsigned short f2bf(float f) {
    __hip_bfloat16 h = __float2bfloat16(f);
    return *(unsigned short*)&h;
}
__device__ __forceinline__ float bf2f(unsigned short u) {
    __hip_bfloat16 h; *(unsigned short*)&h = u;
    return __bfloat162float(h);
}

// conv1 output layout (per image): 2 bf16 planes of 6400 ushorts (12800B each).
// Plane = 196 compact pixels (14x14) x 32ch, granule = 64B, slot-swizzled:
// off = p*32 + (((oc>>3) ^ (p>>1)) & 3)*8 + (oc&7).  Granules 196..199 zeroed
// (conv2's OOB-redirect target).  Image stride = 12800 ushorts.
// bf16x2/3-product numerics: dropped a2b2 term <= 2^-18 * sum|a||b| ~ 3e-5 on
// conv2 outputs -- 16x below the measured 6-product absmax (4.9e-4).

// ---------------- conv1 (1->32, 5x5 SAME) + relu + 2x2 maxpool ----------------
__global__ __launch_bounds__(256) void conv1_pool(const float* __restrict__ image,
                                                  const float* __restrict__ limg,
                                                  const float* __restrict__ wt,
                                                  const float* __restrict__ bias,
                                                  unsigned short* __restrict__ o1b) {
    const int n = blockIdx.x;
    const float* in = (n < BATCH) ? (image + (size_t)n * 784)
                                  : (limg + (size_t)(n - BATCH) * 784);
    __shared__ float pin[32][32];
    __shared__ float wts[32 * 25];
    const int tid = threadIdx.x;
    unsigned short* ob = o1b + (size_t)n * 12800;
    for (int i = tid; i < 256; i += 256) {            // zero spare granules
        int pl_ = i >> 7, r = i & 127;
        ob[pl_ * 6400 + 6272 + r] = 0;
    }
    for (int idx = tid; idx < 32 * 32; idx += 256) ((float*)pin)[idx] = 0.f;
    __syncthreads();
    for (int idx = tid; idx < 784; idx += 256) {
        int y = idx / 28, x = idx % 28;
        pin[y + 2][x + 2] = in[idx];
    }
    for (int idx = tid; idx < 800; idx += 256) wts[idx] = wt[idx];
    __syncthreads();
    const int oc = tid & 31;
    float wk[25];
    #pragma unroll
    for (int k = 0; k < 25; ++k) wk[k] = wts[oc * 25 + k];
    float b = bias[oc];
    const int slot_lo = (oc & 7);
    const int gq = oc >> 3;
    for (int o = tid; o < 6272; o += 256) {
        int p = o >> 5, py = p / 14, px = p % 14;
        float win[6][6];
        #pragma unroll
        for (int r = 0; r < 6; ++r)
        #pragma unroll
        for (int c = 0; c < 6; ++c)
            win[r][c] = pin[2 * py + r][2 * px + c];
        float a00 = b, a01 = b, a10 = b, a11 = b;
        #pragma unroll
        for (int ky = 0; ky < 5; ++ky)
        #pragma unroll
        for (int kx = 0; kx < 5; ++kx) {
            float w = wk[ky * 5 + kx];
            a00 = fmaf(win[ky][kx], w, a00);
            a01 = fmaf(win[ky][kx + 1], w, a01);
            a10 = fmaf(win[ky + 1][kx], w, a10);
            a11 = fmaf(win[ky + 1][kx + 1], w, a11);
        }
        float v = fmaxf(fmaxf(fmaxf(a00, a01), fmaxf(a10, a11)), 0.f);
        unsigned short b1 = f2bf(v); float r1 = v - bf2f(b1);
        unsigned short b2 = f2bf(r1);
        int off = p * 32 + (((gq ^ (p >> 1)) & 3) << 3) + slot_lo;
        ob[off] = b1; ob[6400 + off] = b2;
    }
}

// ---------------- B fragment prep for conv2: bf16x2 ---------------------------
__global__ __launch_bounds__(256) void bprep(const float* __restrict__ w,
                                             unsigned short* __restrict__ Bf) {
    int idx = blockIdx.x * 256 + threadIdx.x;   // 50*2*2*512 = 102400
    if (idx >= 102400) return;
    int j = idx & 7, lane = (idx >> 3) & 63, ocT = (idx >> 9) & 1, s = idx >> 10;
    int q = lane >> 5, nn = lane & 31;
    int k = 16 * s + 8 * q + j;
    int tap = k >> 5, ic = k & 31;
    int oc = 32 * ocT + nn;
    float v = w[oc * 800 + ic * 25 + tap];
    unsigned short b1 = f2bf(v);
    unsigned short b2 = f2bf(v - bf2f(b1));
    size_t base = ((size_t)(s * 2 + ocT) * 2) * 512 + lane * 8 + j;
    Bf[base] = b1; Bf[base + 512] = b2;
}

// ---------------- f1w prep: bf16x3 planes Bw3[pl][512][3136] ------------------
#define BSTR ((size_t)512 * 3136)
#define ASTR ((size_t)NTOT * 3136)
__global__ __launch_bounds__(256) void wprep(const float* __restrict__ w,
                                             unsigned short* __restrict__ B3) {
    int idx = blockIdx.x * 256 + threadIdx.x;   // 512*3136
    if (idx >= 512 * 3136) return;
    float v = w[idx];
    unsigned short b1 = f2bf(v);
    float r1 = v - bf2f(b1);
    unsigned short b2 = f2bf(r1);
    unsigned short b3 = f2bf(r1 - bf2f(b2));
    B3[idx] = b1; B3[BSTR + idx] = b2; B3[2 * BSTR + idx] = b3;
}

// ---------------- conv2 via MFMA, v6: bf16x2 / 3 products ---------------------
// r10 structure (4 waves = ocT x kh, K-split 25+25, proven fastest) with half
// the MFMA work: products a1b1, a1b2, a2b1 (a2b2 dropped, bound ~3e-5).
// LDS 25.6KB (2 planes); K-merge in 3 phases of <=3 tiles (6144 floats).
__global__ __launch_bounds__(256) void conv2_mfma(const unsigned short* __restrict__ o1b,
                                                  const unsigned short* __restrict__ Bf,
                                                  const float* __restrict__ bias,
                                                  unsigned short* __restrict__ out3) {
    const int n = blockIdx.x;
    __shared__ __align__(16) unsigned short pl[12800];   // 25,600B
    const int tid = threadIdx.x;
    const int lane = tid & 63, wv = tid >> 6;
    const int ocT = wv & 1, kh = wv >> 1;

    // ---- stage: linear copy (planes already split + swizzled by conv1) ----
    {
        const float4* src = (const float4*)(o1b + (size_t)n * 12800);
        float4* dst = (float4*)pl;
        for (int i = tid; i < 1600; i += 256) dst[i] = src[i];
    }
    __syncthreads();

    const int m_ = lane & 31, q = lane >> 5;
    int ym[7], xm[7], mm[7];
    #pragma unroll
    for (int t = 0; t < 7; ++t) {
        int m = 32 * t + m_;
        mm[t] = m;
        ym[t] = m / 14;
        xm[t] = m - 14 * ym[t];
    }
    f32x16 acc[7];
    {
        float bs = (kh == 0) ? bias[32 * ocT + m_] : 0.f;
        #pragma unroll
        for (int t = 0; t < 7; ++t)
        #pragma unroll
        for (int r = 0; r < 16; ++r) acc[t][r] = bs;
    }

    for (int s = kh * 25; s < kh * 25 + 25; ++s) {
        const unsigned short* bp = Bf + ((size_t)(s * 2 + ocT) * 2) * 512 + lane * 8;
        short8 b1 = *(const short8*)(bp);
        short8 b2 = *(const short8*)(bp + 512);
        int kb = 16 * s + 8 * q;
        int tap = kb >> 5, ic0 = kb & 31, g = ic0 >> 3;
        int ky = (tap * 13) >> 6;       // exact /5 for tap<25
        int kx = tap - ky * 5;
        int iyk = ky - 2, ixk = kx - 2;
        int pq2 = iyk * 14 + ixk;
        short8 a1[7], a2[7];
        #pragma unroll
        for (int t = 0; t < 7; ++t) {
            int iy = ym[t] + iyk, ix = xm[t] + ixk;
            int valid = ((unsigned)iy < 14u) & ((unsigned)ix < 14u);
            int cpt = valid ? (mm[t] + pq2) : 196;
            int addr = cpt * 32 + (((g ^ (cpt >> 1)) & 3) << 3);
            a1[t] = *(const short8*)(pl + addr);
            a2[t] = *(const short8*)(pl + 6400 + addr);
        }
        #pragma unroll
        for (int t = 0; t < 7; ++t)
            acc[t] = __builtin_amdgcn_mfma_f32_32x32x16_bf16(a1[t], b1, acc[t], 0, 0, 0);
        #pragma unroll
        for (int t = 0; t < 7; ++t)
            acc[t] = __builtin_amdgcn_mfma_f32_32x32x16_bf16(a1[t], b2, acc[t], 0, 0, 0);
        #pragma unroll
        for (int t = 0; t < 7; ++t)
            acc[t] = __builtin_amdgcn_mfma_f32_32x32x16_bf16(a2[t], b1, acc[t], 0, 0, 0);
    }
    __syncthreads();   // planes dead

    // ---- merge K halves through LDS, 3 phases of <=3 tiles (6144 floats) ----
    float* accbuf = (float*)pl;    // 6400 floats available
    #pragma unroll
    for (int ph = 0; ph < 3; ++ph) {
        const int t0 = 3 * ph;
        const int tn = (ph == 2) ? 1 : 3;
        if (kh == 0) {
            for (int t = t0; t < t0 + tn; ++t)
                #pragma unroll
                for (int r = 0; r < 16; ++r)
                    accbuf[((ocT * tn + (t - t0)) * 16 + r) * 64 + lane] = acc[t][r];
        }
        __syncthreads();
        if (kh == 1) {
            for (int t = t0; t < t0 + tn; ++t)
                #pragma unroll
                for (int r = 0; r < 16; ++r)
                    acc[t][r] += accbuf[((ocT * tn + (t - t0)) * 16 + r) * 64 + lane];
        }
        __syncthreads();
    }

    // ---- x-pool in-lane (kh=1 waves) -> hx[y][px][oc], stride 65 ----
    float* hx = (float*)pl;        // 3183 floats, fits (post-sync alias)
    if (kh == 1) {
        const int oc = 32 * ocT + m_;
        #pragma unroll
        for (int t = 0; t < 7; ++t)
        #pragma unroll
        for (int e = 0; e < 8; ++e) {
            const int reg = 2 * e;
            const int r = (reg & 3) + 8 * (reg >> 2) + 4 * q;
            const int m = 32 * t + r;
            if (m < 196) {
                float xm2 = fmaxf(acc[t][reg], acc[t][reg + 1]);
                int y = (m * 2341) >> 15;        // /14
                int px = (m - 14 * y) >> 1;
                hx[(y * 7 + px) * 65 + oc] = xm2;
            }
        }
    }
    __syncthreads();

    // ---- y-pool + relu + bf16x3 store (fc1 input path unchanged) ----
    const size_t OSTR = ASTR;
    for (int idx = tid; idx < 3136; idx += 256) {
        int oc2 = (idx * 2675) >> 17;        // /49
        int p = idx - 49 * oc2;
        int py = (p * 9363) >> 16;           // /7
        int px = p - 7 * py;
        float v = fmaxf(hx[(2 * py * 7 + px) * 65 + oc2],
                        hx[((2 * py + 1) * 7 + px) * 65 + oc2]);
        v = fmaxf(v, 0.f);
        unsigned short b1 = f2bf(v);
        float r1 = v - bf2f(b1);
        unsigned short b2 = f2bf(r1);
        unsigned short b3 = f2bf(r1 - bf2f(b2));
        size_t o = (size_t)n * 3136 + idx;
        out3[o] = b1; out3[OSTR + o] = b2; out3[2 * OSTR + o] = b3;
    }
}

// ---------------- fc1 via MFMA (bf16x3, 6 products), split-K=7 ----------------
__global__ __launch_bounds__(256) void fc1_mfma(const unsigned short* __restrict__ A3,
                                                const unsigned short* __restrict__ B3,
                                                float* __restrict__ part) {
    __shared__ unsigned short As[3][2048];
    __shared__ unsigned short Bs[3][2048];
    const int tid = threadIdx.x;
    const int n0 = blockIdx.x * 64, m0 = blockIdx.y * 64;
    const int koff = blockIdx.z * 448;
    const int lr = tid >> 2, g = tid & 3;
    const int slot = (((g ^ (lr >> 1)) & 3) << 3);
    const int lane = tid & 63, wv = tid >> 6;
    const int nq = wv & 1, mq = wv >> 1;
    const int q = lane >> 5, l31 = lane & 31;
    const int rA = 32 * nq + l31, rB = 32 * mq + l31;
    f32x16 acc;
    #pragma unroll
    for (int r = 0; r < 16; ++r) acc[r] = 0.f;

    for (int bk = 0; bk < 448; bk += 32) {
        const size_t ka = (size_t)(koff + bk + (g << 3));
        short8 av[3], bv[3];
        #pragma unroll
        for (int p = 0; p < 3; ++p) {
            av[p] = *(const short8*)(A3 + p * ASTR + (size_t)(n0 + lr) * 3136 + ka);
            bv[p] = *(const short8*)(B3 + p * BSTR + (size_t)(m0 + lr) * 3136 + ka);
        }
        __syncthreads();
        #pragma unroll
        for (int p = 0; p < 3; ++p) {
            *(short8*)&As[p][(lr << 5) + slot] = av[p];
            *(short8*)&Bs[p][(lr << 5) + slot] = bv[p];
        }
        __syncthreads();
        #pragma unroll
        for (int s2 = 0; s2 < 32; s2 += 16) {
            const int gg = (s2 + (q << 3)) >> 3;
            const int sa = (((gg ^ (rA >> 1)) & 3) << 3);
            const int sb = (((gg ^ (rB >> 1)) & 3) << 3);
            short8 a1 = *(const short8*)&As[0][(rA << 5) + sa];
            short8 a2 = *(const short8*)&As[1][(rA << 5) + sa];
            short8 a3 = *(const short8*)&As[2][(rA << 5) + sa];
            short8 b1 = *(const short8*)&Bs[0][(rB << 5) + sb];
            short8 b2 = *(const short8*)&Bs[1][(rB << 5) + sb];
            short8 b3 = *(const short8*)&Bs[2][(rB << 5) + sb];
            acc = __builtin_amdgcn_mfma_f32_32x32x16_bf16(a1, b1, acc, 0, 0, 0);
            acc = __builtin_amdgcn_mfma_f32_32x32x16_bf16(a1, b2, acc, 0, 0, 0);
            acc = __builtin_amdgcn_mfma_f32_32x32x16_bf16(a2, b1, acc, 0, 0, 0);
            acc = __builtin_amdgcn_mfma_f32_32x32x16_bf16(a2, b2, acc, 0, 0, 0);
            acc = __builtin_amdgcn_mfma_f32_32x32x16_bf16(a1, b3, acc, 0, 0, 0);
            acc = __builtin_amdgcn_mfma_f32_32x32x16_bf16(a3, b1, acc, 0, 0, 0);
        }
    }
    float* pb = part + (size_t)blockIdx.z * NTOT * 512;
    #pragma unroll
    for (int reg = 0; reg < 16; ++reg) {
        int nn = n0 + 32 * nq + (reg & 3) + 8 * (reg >> 2) + 4 * q;
        int mmo = m0 + 32 * mq + l31;
        pb[(size_t)nn * 512 + mmo] = acc[reg];
    }
}

__global__ __launch_bounds__(256) void fc1_reduce(const float* __restrict__ part,
                                                  const float* __restrict__ bias,
                                                  float* __restrict__ lat,
                                                  float* __restrict__ rep) {
    int idx = blockIdx.x * 256 + threadIdx.x;
    int m = idx & 511;
    float v = bias[m];
    #pragma unroll
    for (int kz = 0; kz < 7; ++kz) v += part[(size_t)kz * NTOT * 512 + idx];
    if (idx < BATCH * 512) lat[idx] = v;
    else rep[idx - BATCH * 512] = tanhf(v);
}

// ---------------- label = softmax(lat @ fcn_w.T + fcn_b) ----------------
__global__ __launch_bounds__(128) void fcn_softmax(const float* __restrict__ lat,
                                                   const float* __restrict__ fw,
                                                   const float* __restrict__ fb,
                                                   float* __restrict__ out) {
    const int b = blockIdx.x;
    const int j = threadIdx.x;
    __shared__ float lrow[512];
    __shared__ float red[128];
    for (int i = j; i < 512; i += 128) lrow[i] = lat[b * 512 + i];
    __syncthreads();
    const float4* w4 = (const float4*)(fw + j * 512);
    float acc = fb[j];
    #pragma unroll 4
    for (int qq = 0; qq < 128; ++qq) {
        float4 a = ((const float4*)lrow)[qq];
        float4 w = w4[qq];
        acc += a.x * w.x + a.y * w.y + a.z * w.z + a.w * w.w;
    }
    red[j] = acc;
    __syncthreads();
    for (int off = 64; off >= 1; off >>= 1) {
        if (j < off) red[j] = fmaxf(red[j], red[j + off]);
        __syncthreads();
    }
    float mx = red[0];
    __syncthreads();
    float ex = expf(acc - mx);
    red[j] = ex;
    __syncthreads();
    for (int off = 64; off >= 1; off >>= 1) {
        if (j < off) red[j] += red[j + off];
        __syncthreads();
    }
    out[b * 128 + j] = ex / red[0];
}

// ---------------- rho / t / w ----------------
__global__ __launch_bounds__(256) void rho_kernel(const float* __restrict__ rep,
                                                  float* __restrict__ rho) {
    __shared__ float red[256];
    const int tid = threadIdx.x;
    float s = 0.f;
    for (int i = tid; i < LABEL * LATENT; i += 256) s += rep[i];
    red[tid] = s;
    __syncthreads();
    for (int off = 128; off >= 1; off >>= 1) {
        if (tid < off) red[tid] += red[tid + off];
        __syncthreads();
    }
    if (tid == 0) rho[0] = red[0] / (float)(LABEL * LATENT);
}

__global__ __launch_bounds__(256) void t_kernel(const float* __restrict__ rep,
                                                const float* __restrict__ rho,
                                                float* __restrict__ tT) {
    int idx = blockIdx.x * 256 + threadIdx.x;
    int i = idx / 128, k = idx % 128;
    tT[idx] = rep[k * 512 + i] - rho[0];
}

__global__ __launch_bounds__(256) void w_kernel(const float* __restrict__ tT,
                                                float* __restrict__ w) {
    int idx = blockIdx.x * 256 + threadIdx.x;
    int i = idx >> 9, j = idx & 511;
    const float4* a = (const float4*)(tT + i * 128);
    const float4* b = (const float4*)(tT + j * 128);
    float acc = 0.f;
    #pragma unroll 8
    for (int q = 0; q < 32; ++q) {
        float4 av = a[q], bv = b[q];
        acc += av.x * bv.x + av.y * bv.y + av.z * bv.z + av.w * bv.w;
    }
    w[idx] = (i == j) ? 0.f : acc * (1.f / 128.f);
}

// ---------------- clustering (r6 proven): incremental Hopfield ----------------
#define CB 4
__device__ __forceinline__ float sgnf(float x) {
    return (x > 0.f) ? 1.f : ((x < 0.f) ? -1.f : 0.f);
}

__global__ __launch_bounds__(256) void clustering(const float* __restrict__ lat,
                                                  const float* __restrict__ w,
                                                  const float* __restrict__ rep,
                                                  float* __restrict__ out) {
    const int tid = threadIdx.x;
    const int row0 = blockIdx.x * CB;
    __shared__ float sbuf[CB][512];
    __shared__ float mins[CB][512];
    __shared__ float red[256];
    __shared__ float part_e[4][CB];
    __shared__ int part_c[4];
    __shared__ float min_e[CB];
    __shared__ int copyf[CB];
    __shared__ int donef[CB];
    __shared__ int cnt[CB];
    __shared__ int jidx[CB][512];
    __shared__ float jdel[CB][512];
    const int i0 = 2 * tid, i1 = 2 * tid + 1;
    const int wave = tid >> 6, lane = tid & 63;

    float sm10[CB], sm11[CB], sm20[CB], sm21[CB], h0[CB], h1[CB];
    #pragma unroll
    for (int r = 0; r < CB; ++r) {
        float a = tanhf(lat[(row0 + r) * 512 + i0]);
        float b = tanhf(lat[(row0 + r) * 512 + i1]);
        sm10[r] = a; sm11[r] = b;
        sm20[r] = a; sm21[r] = b;
        sbuf[r][i0] = a; sbuf[r][i1] = b;
        h0[r] = 0.f; h1[r] = 0.f;
    }
    if (tid < CB) { min_e[tid] = INFINITY; donef[tid] = 0; cnt[tid] = 0; }
    __syncthreads();

    #pragma unroll 4
    for (int j = 0; j < 512; ++j) {
        float2 wvv = *(const float2*)(w + (size_t)j * 512 + i0);
        #pragma unroll
        for (int r = 0; r < CB; ++r) {
            float sj = sbuf[r][j];
            h0[r] = fmaf(sj, wvv.x, h0[r]);
            h1[r] = fmaf(sj, wvv.y, h1[r]);
        }
    }

    for (int k = 1; k <= 512; ++k) {
        float sn0[CB], sn1[CB];
        int cy = 0xF;
        #pragma unroll
        for (int r = 0; r < CB; ++r) {
            int dn = donef[r];
            if (dn) {
                sn0[r] = sm10[r]; sn1[r] = sm11[r];
            } else {
                sn0[r] = fabsf(sm10[r]) * sgnf(h0[r]);
                sn1[r] = fabsf(sm11[r]) * sgnf(h1[r]);
                if (!(sn0[r] == sm20[r] && sn1[r] == sm21[r])) cy &= ~(1 << r);
                if (sn0[r] != sm10[r]) {
                    int p = atomicAdd(&cnt[r], 1);
                    jidx[r][p] = i0; jdel[r][p] = sn0[r] - sm10[r];
                }
                if (sn1[r] != sm11[r]) {
                    int p = atomicAdd(&cnt[r], 1);
                    jidx[r][p] = i1; jdel[r][p] = sn1[r] - sm11[r];
                }
            }
        }
        #pragma unroll
        for (int m = 32; m >= 1; m >>= 1) cy &= __shfl_xor(cy, m, 64);
        if (lane == 0) part_c[wave] = cy;
        __syncthreads();

        #pragma unroll
        for (int r = 0; r < CB; ++r) {
            const int c = cnt[r];
            for (int t = 0; t < c; ++t) {
                const int j = jidx[r][t];
                const float d = jdel[r][t];
                const float2 wvv = *(const float2*)(w + (size_t)j * 512 + i0);
                h0[r] = fmaf(d, wvv.x, h0[r]);
                h1[r] = fmaf(d, wvv.y, h1[r]);
            }
        }
        float ep[CB];
        #pragma unroll
        for (int r = 0; r < CB; ++r) ep[r] = sn0[r] * h0[r] + sn1[r] * h1[r];
        #pragma unroll
        for (int m = 32; m >= 1; m >>= 1) {
            #pragma unroll
            for (int r = 0; r < CB; ++r) ep[r] += __shfl_xor(ep[r], m, 64);
        }
        if (lane == 0) {
            #pragma unroll
            for (int r = 0; r < CB; ++r) part_e[wave][r] = ep[r];
        }
        __syncthreads();

        if (tid < CB) {
            int r = tid;
            if (!donef[r]) {
                float e = -(part_e[0][r] + part_e[1][r] + part_e[2][r] + part_e[3][r]);
                int better = e < min_e[r];
                if (better) min_e[r] = e;
                copyf[r] = better;
                int fl = part_c[0] & part_c[1] & part_c[2] & part_c[3];
                int fixedp = (cnt[r] == 0);
                int cyc = (k >= 2) && ((fl >> r) & 1);
                if (fixedp || cyc) donef[r] = 1;
            } else {
                copyf[r] = 0;
            }
            cnt[r] = 0;
        }
        __syncthreads();

        int alldone = 1;
        #pragma unroll
        for (int r = 0; r < CB; ++r) {
            if (copyf[r]) { mins[r][i0] = sn0[r]; mins[r][i1] = sn1[r]; }
            alldone &= donef[r];
            sm20[r] = sm10[r]; sm21[r] = sm11[r];
            sm10[r] = sn0[r];  sm11[r] = sn1[r];
        }
        if (alldone) break;
    }
    __syncthreads();

    const int j = tid & 127, half = tid >> 7;
    for (int r = 0; r < CB; ++r) {
        const float4* rr = (const float4*)(rep + (size_t)j * 512 + half * 256);
        const float4* ms = (const float4*)(&mins[r][half * 256]);
        float p = 0.f;
        #pragma unroll 8
        for (int q = 0; q < 64; ++q) {
            float4 rv = rr[q], mv = ms[q];
            p += rv.x * mv.x + rv.y * mv.y + rv.z * mv.z + rv.w * mv.w;
        }
        red[tid] = p;
        __syncthreads();
        float v = 0.f;
        if (tid < 128) { v = fabsf(red[tid] + red[tid + 128]); red[tid] = v; }
        __syncthreads();
        for (int off = 64; off >= 1; off >>= 1) {
            if (tid < off) red[tid] = fmaxf(red[tid], red[tid + off]);
            __syncthreads();
        }
        float mx = red[0];
        __syncthreads();
        float ex = 0.f;
        if (tid < 128) { ex = expf(v - mx); red[tid] = ex; }
        __syncthreads();
        for (int off = 64; off >= 1; off >>= 1) {
            if (tid < off) red[tid] += red[tid + off];
            __syncthreads();
        }
        if (tid < 128) out[(size_t)(row0 + r) * 128 + tid] = ex / red[0];
        __syncthreads();
    }
}

extern "C" void kernel_launch(void* const* d_in, const int* in_sizes, int n_in,
                              void* d_out, int out_size, void* d_ws, size_t ws_size,
                              hipStream_t stream) {
    const float* image = (const float*)d_in[0];
    const float* limg  = (const float*)d_in[1];
    const float* c1w   = (const float*)d_in[2];
    const float* c1b   = (const float*)d_in[3];
    const float* c2w   = (const float*)d_in[4];
    const float* c2b   = (const float*)d_in[5];
    const float* f1w   = (const float*)d_in[6];
    const float* f1b   = (const float*)d_in[7];
    const float* fnw   = (const float*)d_in[8];
    const float* fnb   = (const float*)d_in[9];
    float* out = (float*)d_out;
    float* ws  = (float*)d_ws;

    unsigned short* o1b  = (unsigned short*)ws;        // 1152*12800 us = 29.5MB
    unsigned short* out3 = o1b + (size_t)NTOT * 12800; // 3*ASTR bf16
    float* lat  = (float*)(out3 + 3 * ASTR);           // 1024*512
    float* rep  = lat + (size_t)BATCH * 512;           // 128*512
    float* tT   = rep + (size_t)LABEL * 512;           // 512*128
    float* wmat = tT + (size_t)512 * 128;              // 512*512
    float* rho  = wmat + (size_t)512 * 512;            // 1 (+pad)
    unsigned short* Bw3   = (unsigned short*)(rho + 16);   // 3*BSTR bf16
    unsigned short* Bfrag = Bw3 + 3 * BSTR;                // 102,400 bf16
    float* part = (float*)ws;                          // alias o1b (dead after conv2)

    hipLaunchKernelGGL(bprep, dim3(400), dim3(256), 0, stream, c2w, Bfrag);
    hipLaunchKernelGGL(wprep, dim3(6272), dim3(256), 0, stream, f1w, Bw3);
    hipLaunchKernelGGL(conv1_pool, dim3(NTOT), dim3(256), 0, stream, image, limg, c1w, c1b, o1b);
    hipLaunchKernelGGL(conv2_mfma, dim3(NTOT), dim3(256), 0, stream, o1b, Bfrag, c2b, out3);
    hipLaunchKernelGGL(fc1_mfma, dim3(NTOT / 64, 512 / 64, 7), dim3(256), 0, stream,
                       out3, Bw3, part);
    hipLaunchKernelGGL(fc1_reduce, dim3(NTOT * 512 / 256), dim3(256), 0, stream,
                       part, f1b, lat, rep);
    hipLaunchKernelGGL(fcn_softmax, dim3(BATCH), dim3(128), 0, stream, lat, fnw, fnb,
                       out + (size_t)BATCH * LABEL);
    hipLaunchKernelGGL(rho_kernel, dim3(1), dim3(256), 0, stream, rep, rho);
    hipLaunchKernelGGL(t_kernel, dim3(256), dim3(256), 0, stream, rep, rho, tT);
    hipLaunchKernelGGL(w_kernel, dim3(1024), dim3(256), 0, stream, tT, wmat);
    hipLaunchKernelGGL(clustering, dim3(BATCH / CB), dim3(256), 0, stream, lat, wmat, rep, out);
}

// Round 13
// 426.152 us; speedup vs baseline: 1.1905x; 1.0482x over previous
//
#include <hip/hip_runtime.h>
#include <hip/hip_bf16.h>
#include <math.h>

#define BATCH 1024
#define LABEL 128
#define LATENT 512
#define NTOT 1152  // 1024 + 128

typedef short short8 __attribute__((ext_vector_type(8)));
typedef float f32x16 __attribute__((ext_vector_type(16)));

__device__ __forceinline__ unsigned short f2bf(float f) {
    __hip_bfloat16 h = __float2bfloat16(f);
    return *(unsigned short*)&h;
}
__device__ __forceinline__ float bf2f(unsigned short u) {
    __hip_bfloat16 h; *(unsigned short*)&h = u;
    return __bfloat162float(h);
}

// conv1 output layout (per image): 2 bf16 planes of 6400 ushorts (12800B each).
// Plane = 196 compact pixels (14x14) x 32ch, granule = 64B, slot-swizzled:
// off = p*32 + (((oc>>3) ^ (p>>1)) & 3)*8 + (oc&7).  Granules 196..199 zeroed
// (conv2's OOB-redirect target).  Image stride = 12800 ushorts.

// ---------------- conv1 (1->32, 5x5 SAME) + relu + 2x2 maxpool ----------------
__global__ __launch_bounds__(256) void conv1_pool(const float* __restrict__ image,
                                                  const float* __restrict__ limg,
                                                  const float* __restrict__ wt,
                                                  const float* __restrict__ bias,
                                                  unsigned short* __restrict__ o1b) {
    const int n = blockIdx.x;
    const float* in = (n < BATCH) ? (image + (size_t)n * 784)
                                  : (limg + (size_t)(n - BATCH) * 784);
    __shared__ float pin[32][32];
    __shared__ float wts[32 * 25];
    const int tid = threadIdx.x;
    unsigned short* ob = o1b + (size_t)n * 12800;
    for (int i = tid; i < 256; i += 256) {            // zero spare granules
        int pl_ = i >> 7, r = i & 127;
        ob[pl_ * 6400 + 6272 + r] = 0;
    }
    for (int idx = tid; idx < 32 * 32; idx += 256) ((float*)pin)[idx] = 0.f;
    __syncthreads();
    for (int idx = tid; idx < 784; idx += 256) {
        int y = idx / 28, x = idx % 28;
        pin[y + 2][x + 2] = in[idx];
    }
    for (int idx = tid; idx < 800; idx += 256) wts[idx] = wt[idx];
    __syncthreads();
    const int oc = tid & 31;
    float wk[25];
    #pragma unroll
    for (int k = 0; k < 25; ++k) wk[k] = wts[oc * 25 + k];
    float b = bias[oc];
    const int slot_lo = (oc & 7);
    const int gq = oc >> 3;
    for (int o = tid; o < 6272; o += 256) {
        int p = o >> 5, py = p / 14, px = p % 14;
        float win[6][6];
        #pragma unroll
        for (int r = 0; r < 6; ++r)
        #pragma unroll
        for (int c = 0; c < 6; ++c)
            win[r][c] = pin[2 * py + r][2 * px + c];
        float a00 = b, a01 = b, a10 = b, a11 = b;
        #pragma unroll
        for (int ky = 0; ky < 5; ++ky)
        #pragma unroll
        for (int kx = 0; kx < 5; ++kx) {
            float w = wk[ky * 5 + kx];
            a00 = fmaf(win[ky][kx], w, a00);
            a01 = fmaf(win[ky][kx + 1], w, a01);
            a10 = fmaf(win[ky + 1][kx], w, a10);
            a11 = fmaf(win[ky + 1][kx + 1], w, a11);
        }
        float v = fmaxf(fmaxf(fmaxf(a00, a01), fmaxf(a10, a11)), 0.f);
        unsigned short b1 = f2bf(v); float r1 = v - bf2f(b1);
        unsigned short b2 = f2bf(r1);
        int off = p * 32 + (((gq ^ (p >> 1)) & 3) << 3) + slot_lo;
        ob[off] = b1; ob[6400 + off] = b2;
    }
}

// ---------------- B fragment prep for conv2: bf16x2 ---------------------------
__global__ __launch_bounds__(256) void bprep(const float* __restrict__ w,
                                             unsigned short* __restrict__ Bf) {
    int idx = blockIdx.x * 256 + threadIdx.x;   // 50*2*2*512 = 102400
    if (idx >= 102400) return;
    int j = idx & 7, lane = (idx >> 3) & 63, ocT = (idx >> 9) & 1, s = idx >> 10;
    int q = lane >> 5, nn = lane & 31;
    int k = 16 * s + 8 * q + j;
    int tap = k >> 5, ic = k & 31;
    int oc = 32 * ocT + nn;
    float v = w[oc * 800 + ic * 25 + tap];
    unsigned short b1 = f2bf(v);
    unsigned short b2 = f2bf(v - bf2f(b1));
    size_t base = ((size_t)(s * 2 + ocT) * 2) * 512 + lane * 8 + j;
    Bf[base] = b1; Bf[base + 512] = b2;
}

// ---------------- f1w prep: bf16x3 planes Bw3[pl][512][3136] ------------------
#define BSTR ((size_t)512 * 3136)
#define ASTR ((size_t)NTOT * 3136)
__global__ __launch_bounds__(256) void wprep(const float* __restrict__ w,
                                             unsigned short* __restrict__ B3) {
    int idx = blockIdx.x * 256 + threadIdx.x;   // 512*3136
    if (idx >= 512 * 3136) return;
    float v = w[idx];
    unsigned short b1 = f2bf(v);
    float r1 = v - bf2f(b1);
    unsigned short b2 = f2bf(r1);
    unsigned short b3 = f2bf(r1 - bf2f(b2));
    B3[idx] = b1; B3[BSTR + idx] = b2; B3[2 * BSTR + idx] = b3;
}

// ---------------- conv2 via MFMA, v7: bf16x2, M-split waves -------------------
// r12 was latency-bound: acc[7]=112 AGPR + 128 VGPR -> 2 waves/SIMD.
// v7: 4 waves = (ocT, mh); wave owns 4 M-tiles (mh=1: 3 + dead) over FULL K.
// acc = 64 AGPR -> ~3 waves/SIMD; K-merge phases + 6 barriers deleted.
// Cost: 2x Bf L2 traffic (+~7us) and 8/7 MFMA -- bought occupancy is worth it.
__global__ __launch_bounds__(256) void conv2_mfma(const unsigned short* __restrict__ o1b,
                                                  const unsigned short* __restrict__ Bf,
                                                  const float* __restrict__ bias,
                                                  unsigned short* __restrict__ out3) {
    const int n = blockIdx.x;
    __shared__ __align__(16) unsigned short pl[12800];   // 25,600B
    const int tid = threadIdx.x;
    const int lane = tid & 63, wv = tid >> 6;
    const int ocT = wv & 1, mh = wv >> 1;

    // ---- stage: linear copy (planes already split + swizzled by conv1) ----
    {
        const float4* src = (const float4*)(o1b + (size_t)n * 12800);
        float4* dst = (float4*)pl;
        for (int i = tid; i < 1600; i += 256) dst[i] = src[i];
    }
    __syncthreads();

    const int m_ = lane & 31, q = lane >> 5;
    int ym[4], xm[4], mm[4], tvv[4];
    #pragma unroll
    for (int tt = 0; tt < 4; ++tt) {
        int t = 4 * mh + tt;            // mh=0: 0..3, mh=1: 4..7 (t=7 dead)
        tvv[tt] = (t < 7);
        int m = 32 * t + m_;
        mm[tt] = m;
        ym[tt] = m / 14;
        xm[tt] = m - 14 * ym[tt];
    }
    f32x16 acc[4];
    {
        float bs = bias[32 * ocT + m_];   // each tile initialized exactly once
        #pragma unroll
        for (int tt = 0; tt < 4; ++tt)
        #pragma unroll
        for (int r = 0; r < 16; ++r) acc[tt][r] = bs;
    }

    for (int s = 0; s < 50; ++s) {
        const unsigned short* bp = Bf + ((size_t)(s * 2 + ocT) * 2) * 512 + lane * 8;
        short8 b1 = *(const short8*)(bp);
        short8 b2 = *(const short8*)(bp + 512);
        int kb = 16 * s + 8 * q;
        int tap = kb >> 5, ic0 = kb & 31, g = ic0 >> 3;
        int ky = (tap * 13) >> 6;       // exact /5 for tap<25
        int kx = tap - ky * 5;
        int iyk = ky - 2, ixk = kx - 2;
        int pq2 = iyk * 14 + ixk;
        short8 a1[4], a2[4];
        #pragma unroll
        for (int tt = 0; tt < 4; ++tt) {
            int iy = ym[tt] + iyk, ix = xm[tt] + ixk;
            int valid = tvv[tt] & ((unsigned)iy < 14u) & ((unsigned)ix < 14u);
            // when valid, cpt = 14*iy + ix <= 195 (identity), so always in-bounds
            int cpt = valid ? (mm[tt] + pq2) : 196;
            int addr = cpt * 32 + (((g ^ (cpt >> 1)) & 3) << 3);
            a1[tt] = *(const short8*)(pl + addr);
            a2[tt] = *(const short8*)(pl + 6400 + addr);
        }
        #pragma unroll
        for (int tt = 0; tt < 4; ++tt)
            acc[tt] = __builtin_amdgcn_mfma_f32_32x32x16_bf16(a1[tt], b1, acc[tt], 0, 0, 0);
        #pragma unroll
        for (int tt = 0; tt < 4; ++tt)
            acc[tt] = __builtin_amdgcn_mfma_f32_32x32x16_bf16(a1[tt], b2, acc[tt], 0, 0, 0);
        #pragma unroll
        for (int tt = 0; tt < 4; ++tt)
            acc[tt] = __builtin_amdgcn_mfma_f32_32x32x16_bf16(a2[tt], b1, acc[tt], 0, 0, 0);
    }
    __syncthreads();   // planes dead

    // ---- x-pool in-lane: every wave writes its own tiles -> hx, stride 65 ----
    float* hx = (float*)pl;        // 6369 floats = 25.5KB, aliases planes
    {
        const int oc = 32 * ocT + m_;
        #pragma unroll
        for (int tt = 0; tt < 4; ++tt)
        #pragma unroll
        for (int e = 0; e < 8; ++e) {
            const int reg = 2 * e;
            const int r = (reg & 3) + 8 * (reg >> 2) + 4 * q;
            const int m = 32 * (4 * mh + tt) + r;
            if (m < 196) {
                float xm2 = fmaxf(acc[tt][reg], acc[tt][reg + 1]);
                int y = (m * 2341) >> 15;        // /14
                int px = (m - 14 * y) >> 1;
                hx[(y * 7 + px) * 65 + oc] = xm2;
            }
        }
    }
    __syncthreads();

    // ---- y-pool + relu + bf16x3 store (fc1 input path unchanged) ----
    const size_t OSTR = ASTR;
    for (int idx = tid; idx < 3136; idx += 256) {
        int oc2 = (idx * 2675) >> 17;        // /49
        int p = idx - 49 * oc2;
        int py = (p * 9363) >> 16;           // /7
        int px = p - 7 * py;
        float v = fmaxf(hx[(2 * py * 7 + px) * 65 + oc2],
                        hx[((2 * py + 1) * 7 + px) * 65 + oc2]);
        v = fmaxf(v, 0.f);
        unsigned short b1 = f2bf(v);
        float r1 = v - bf2f(b1);
        unsigned short b2 = f2bf(r1);
        unsigned short b3 = f2bf(r1 - bf2f(b2));
        size_t o = (size_t)n * 3136 + idx;
        out3[o] = b1; out3[OSTR + o] = b2; out3[2 * OSTR + o] = b3;
    }
}

// ---------------- fc1 via MFMA (bf16x3, 6 products), split-K=7 ----------------
__global__ __launch_bounds__(256) void fc1_mfma(const unsigned short* __restrict__ A3,
                                                const unsigned short* __restrict__ B3,
                                                float* __restrict__ part) {
    __shared__ unsigned short As[3][2048];
    __shared__ unsigned short Bs[3][2048];
    const int tid = threadIdx.x;
    const int n0 = blockIdx.x * 64, m0 = blockIdx.y * 64;
    const int koff = blockIdx.z * 448;
    const int lr = tid >> 2, g = tid & 3;
    const int slot = (((g ^ (lr >> 1)) & 3) << 3);
    const int lane = tid & 63, wv = tid >> 6;
    const int nq = wv & 1, mq = wv >> 1;
    const int q = lane >> 5, l31 = lane & 31;
    const int rA = 32 * nq + l31, rB = 32 * mq + l31;
    f32x16 acc;
    #pragma unroll
    for (int r = 0; r < 16; ++r) acc[r] = 0.f;

    for (int bk = 0; bk < 448; bk += 32) {
        const size_t ka = (size_t)(koff + bk + (g << 3));
        short8 av[3], bv[3];
        #pragma unroll
        for (int p = 0; p < 3; ++p) {
            av[p] = *(const short8*)(A3 + p * ASTR + (size_t)(n0 + lr) * 3136 + ka);
            bv[p] = *(const short8*)(B3 + p * BSTR + (size_t)(m0 + lr) * 3136 + ka);
        }
        __syncthreads();
        #pragma unroll
        for (int p = 0; p < 3; ++p) {
            *(short8*)&As[p][(lr << 5) + slot] = av[p];
            *(short8*)&Bs[p][(lr << 5) + slot] = bv[p];
        }
        __syncthreads();
        #pragma unroll
        for (int s2 = 0; s2 < 32; s2 += 16) {
            const int gg = (s2 + (q << 3)) >> 3;
            const int sa = (((gg ^ (rA >> 1)) & 3) << 3);
            const int sb = (((gg ^ (rB >> 1)) & 3) << 3);
            short8 a1 = *(const short8*)&As[0][(rA << 5) + sa];
            short8 a2 = *(const short8*)&As[1][(rA << 5) + sa];
            short8 a3 = *(const short8*)&As[2][(rA << 5) + sa];
            short8 b1 = *(const short8*)&Bs[0][(rB << 5) + sb];
            short8 b2 = *(const short8*)&Bs[1][(rB << 5) + sb];
            short8 b3 = *(const short8*)&Bs[2][(rB << 5) + sb];
            acc = __builtin_amdgcn_mfma_f32_32x32x16_bf16(a1, b1, acc, 0, 0, 0);
            acc = __builtin_amdgcn_mfma_f32_32x32x16_bf16(a1, b2, acc, 0, 0, 0);
            acc = __builtin_amdgcn_mfma_f32_32x32x16_bf16(a2, b1, acc, 0, 0, 0);
            acc = __builtin_amdgcn_mfma_f32_32x32x16_bf16(a2, b2, acc, 0, 0, 0);
            acc = __builtin_amdgcn_mfma_f32_32x32x16_bf16(a1, b3, acc, 0, 0, 0);
            acc = __builtin_amdgcn_mfma_f32_32x32x16_bf16(a3, b1, acc, 0, 0, 0);
        }
    }
    float* pb = part + (size_t)blockIdx.z * NTOT * 512;
    #pragma unroll
    for (int reg = 0; reg < 16; ++reg) {
        int nn = n0 + 32 * nq + (reg & 3) + 8 * (reg >> 2) + 4 * q;
        int mmo = m0 + 32 * mq + l31;
        pb[(size_t)nn * 512 + mmo] = acc[reg];
    }
}

__global__ __launch_bounds__(256) void fc1_reduce(const float* __restrict__ part,
                                                  const float* __restrict__ bias,
                                                  float* __restrict__ lat,
                                                  float* __restrict__ rep) {
    int idx = blockIdx.x * 256 + threadIdx.x;
    int m = idx & 511;
    float v = bias[m];
    #pragma unroll
    for (int kz = 0; kz < 7; ++kz) v += part[(size_t)kz * NTOT * 512 + idx];
    if (idx < BATCH * 512) lat[idx] = v;
    else rep[idx - BATCH * 512] = tanhf(v);
}

// ---------------- label = softmax(lat @ fcn_w.T + fcn_b) ----------------
__global__ __launch_bounds__(128) void fcn_softmax(const float* __restrict__ lat,
                                                   const float* __restrict__ fw,
                                                   const float* __restrict__ fb,
                                                   float* __restrict__ out) {
    const int b = blockIdx.x;
    const int j = threadIdx.x;
    __shared__ float lrow[512];
    __shared__ float red[128];
    for (int i = j; i < 512; i += 128) lrow[i] = lat[b * 512 + i];
    __syncthreads();
    const float4* w4 = (const float4*)(fw + j * 512);
    float acc = fb[j];
    #pragma unroll 4
    for (int qq = 0; qq < 128; ++qq) {
        float4 a = ((const float4*)lrow)[qq];
        float4 w = w4[qq];
        acc += a.x * w.x + a.y * w.y + a.z * w.z + a.w * w.w;
    }
    red[j] = acc;
    __syncthreads();
    for (int off = 64; off >= 1; off >>= 1) {
        if (j < off) red[j] = fmaxf(red[j], red[j + off]);
        __syncthreads();
    }
    float mx = red[0];
    __syncthreads();
    float ex = expf(acc - mx);
    red[j] = ex;
    __syncthreads();
    for (int off = 64; off >= 1; off >>= 1) {
        if (j < off) red[j] += red[j + off];
        __syncthreads();
    }
    out[b * 128 + j] = ex / red[0];
}

// ---------------- rho / t / w ----------------
__global__ __launch_bounds__(256) void rho_kernel(const float* __restrict__ rep,
                                                  float* __restrict__ rho) {
    __shared__ float red[256];
    const int tid = threadIdx.x;
    float s = 0.f;
    for (int i = tid; i < LABEL * LATENT; i += 256) s += rep[i];
    red[tid] = s;
    __syncthreads();
    for (int off = 128; off >= 1; off >>= 1) {
        if (tid < off) red[tid] += red[tid + off];
        __syncthreads();
    }
    if (tid == 0) rho[0] = red[0] / (float)(LABEL * LATENT);
}

__global__ __launch_bounds__(256) void t_kernel(const float* __restrict__ rep,
                                                const float* __restrict__ rho,
                                                float* __restrict__ tT) {
    int idx = blockIdx.x * 256 + threadIdx.x;
    int i = idx / 128, k = idx % 128;
    tT[idx] = rep[k * 512 + i] - rho[0];
}

__global__ __launch_bounds__(256) void w_kernel(const float* __restrict__ tT,
                                                float* __restrict__ w) {
    int idx = blockIdx.x * 256 + threadIdx.x;
    int i = idx >> 9, j = idx & 511;
    const float4* a = (const float4*)(tT + i * 128);
    const float4* b = (const float4*)(tT + j * 128);
    float acc = 0.f;
    #pragma unroll 8
    for (int q = 0; q < 32; ++q) {
        float4 av = a[q], bv = b[q];
        acc += av.x * bv.x + av.y * bv.y + av.z * bv.z + av.w * bv.w;
    }
    w[idx] = (i == j) ? 0.f : acc * (1.f / 128.f);
}

// ---------------- clustering: incremental Hopfield, CB=2 + unrolled loads -----
// CB 4->2: 512 blocks (2/CU), halves per-block serial flip work + tail
// imbalance (block waits on max over CB rows). Flip-loop unroll 4 / initial
// matvec unroll 8 put multiple ~200-cyc L2 w-row loads in flight.
#define CB 2
__device__ __forceinline__ float sgnf(float x) {
    return (x > 0.f) ? 1.f : ((x < 0.f) ? -1.f : 0.f);
}

__global__ __launch_bounds__(256) void clustering(const float* __restrict__ lat,
                                                  const float* __restrict__ w,
                                                  const float* __restrict__ rep,
                                                  float* __restrict__ out) {
    const int tid = threadIdx.x;
    const int row0 = blockIdx.x * CB;
    __shared__ float sbuf[CB][512];
    __shared__ float mins[CB][512];
    __shared__ float red[256];
    __shared__ float part_e[4][CB];
    __shared__ int part_c[4];
    __shared__ float min_e[CB];
    __shared__ int copyf[CB];
    __shared__ int donef[CB];
    __shared__ int cnt[CB];
    __shared__ int jidx[CB][512];
    __shared__ float jdel[CB][512];
    const int i0 = 2 * tid, i1 = 2 * tid + 1;
    const int wave = tid >> 6, lane = tid & 63;

    float sm10[CB], sm11[CB], sm20[CB], sm21[CB], h0[CB], h1[CB];
    #pragma unroll
    for (int r = 0; r < CB; ++r) {
        float a = tanhf(lat[(row0 + r) * 512 + i0]);
        float b = tanhf(lat[(row0 + r) * 512 + i1]);
        sm10[r] = a; sm11[r] = b;
        sm20[r] = a; sm21[r] = b;
        sbuf[r][i0] = a; sbuf[r][i1] = b;
        h0[r] = 0.f; h1[r] = 0.f;
    }
    if (tid < CB) { min_e[tid] = INFINITY; donef[tid] = 0; cnt[tid] = 0; }
    __syncthreads();

    #pragma unroll 8
    for (int j = 0; j < 512; ++j) {
        float2 wvv = *(const float2*)(w + (size_t)j * 512 + i0);
        #pragma unroll
        for (int r = 0; r < CB; ++r) {
            float sj = sbuf[r][j];
            h0[r] = fmaf(sj, wvv.x, h0[r]);
            h1[r] = fmaf(sj, wvv.y, h1[r]);
        }
    }

    for (int k = 1; k <= 512; ++k) {
        float sn0[CB], sn1[CB];
        int cy = (1 << CB) - 1;
        #pragma unroll
        for (int r = 0; r < CB; ++r) {
            int dn = donef[r];
            if (dn) {
                sn0[r] = sm10[r]; sn1[r] = sm11[r];
            } else {
                sn0[r] = fabsf(sm10[r]) * sgnf(h0[r]);
                sn1[r] = fabsf(sm11[r]) * sgnf(h1[r]);
                if (!(sn0[r] == sm20[r] && sn1[r] == sm21[r])) cy &= ~(1 << r);
                if (sn0[r] != sm10[r]) {
                    int p = atomicAdd(&cnt[r], 1);
                    jidx[r][p] = i0; jdel[r][p] = sn0[r] - sm10[r];
                }
                if (sn1[r] != sm11[r]) {
                    int p = atomicAdd(&cnt[r], 1);
                    jidx[r][p] = i1; jdel[r][p] = sn1[r] - sm11[r];
                }
            }
        }
        #pragma unroll
        for (int m = 32; m >= 1; m >>= 1) cy &= __shfl_xor(cy, m, 64);
        if (lane == 0) part_c[wave] = cy;
        __syncthreads();

        #pragma unroll
        for (int r = 0; r < CB; ++r) {
            const int c = cnt[r];
            #pragma unroll 4
            for (int t = 0; t < c; ++t) {
                const int j = jidx[r][t];
                const float d = jdel[r][t];
                const float2 wvv = *(const float2*)(w + (size_t)j * 512 + i0);
                h0[r] = fmaf(d, wvv.x, h0[r]);
                h1[r] = fmaf(d, wvv.y, h1[r]);
            }
        }
        float ep[CB];
        #pragma unroll
        for (int r = 0; r < CB; ++r) ep[r] = sn0[r] * h0[r] + sn1[r] * h1[r];
        #pragma unroll
        for (int m = 32; m >= 1; m >>= 1) {
            #pragma unroll
            for (int r = 0; r < CB; ++r) ep[r] += __shfl_xor(ep[r], m, 64);
        }
        if (lane == 0) {
            #pragma unroll
            for (int r = 0; r < CB; ++r) part_e[wave][r] = ep[r];
        }
        __syncthreads();

        if (tid < CB) {
            int r = tid;
            if (!donef[r]) {
                float e = -(part_e[0][r] + part_e[1][r] + part_e[2][r] + part_e[3][r]);
                int better = e < min_e[r];
                if (better) min_e[r] = e;
                copyf[r] = better;
                int fl = part_c[0] & part_c[1] & part_c[2] & part_c[3];
                int fixedp = (cnt[r] == 0);
                int cyc = (k >= 2) && ((fl >> r) & 1);
                if (fixedp || cyc) donef[r] = 1;
            } else {
                copyf[r] = 0;
            }
            cnt[r] = 0;
        }
        __syncthreads();

        int alldone = 1;
        #pragma unroll
        for (int r = 0; r < CB; ++r) {
            if (copyf[r]) { mins[r][i0] = sn0[r]; mins[r][i1] = sn1[r]; }
            alldone &= donef[r];
            sm20[r] = sm10[r]; sm21[r] = sm11[r];
            sm10[r] = sn0[r];  sm11[r] = sn1[r];
        }
        if (alldone) break;
    }
    __syncthreads();

    const int j = tid & 127, half = tid >> 7;
    for (int r = 0; r < CB; ++r) {
        const float4* rr = (const float4*)(rep + (size_t)j * 512 + half * 256);
        const float4* ms = (const float4*)(&mins[r][half * 256]);
        float p = 0.f;
        #pragma unroll 8
        for (int q = 0; q < 64; ++q) {
            float4 rv = rr[q], mv = ms[q];
            p += rv.x * mv.x + rv.y * mv.y + rv.z * mv.z + rv.w * mv.w;
        }
        red[tid] = p;
        __syncthreads();
        float v = 0.f;
        if (tid < 128) { v = fabsf(red[tid] + red[tid + 128]); red[tid] = v; }
        __syncthreads();
        for (int off = 64; off >= 1; off >>= 1) {
            if (tid < off) red[tid] = fmaxf(red[tid], red[tid + off]);
            __syncthreads();
        }
        float mx = red[0];
        __syncthreads();
        float ex = 0.f;
        if (tid < 128) { ex = expf(v - mx); red[tid] = ex; }
        __syncthreads();
        for (int off = 64; off >= 1; off >>= 1) {
            if (tid < off) red[tid] += red[tid + off];
            __syncthreads();
        }
        if (tid < 128) out[(size_t)(row0 + r) * 128 + tid] = ex / red[0];
        __syncthreads();
    }
}

extern "C" void kernel_launch(void* const* d_in, const int* in_sizes, int n_in,
                              void* d_out, int out_size, void* d_ws, size_t ws_size,
                              hipStream_t stream) {
    const float* image = (const float*)d_in[0];
    const float* limg  = (const float*)d_in[1];
    const float* c1w   = (const float*)d_in[2];
    const float* c1b   = (const float*)d_in[3];
    const float* c2w   = (const float*)d_in[4];
    const float* c2b   = (const float*)d_in[5];
    const float* f1w   = (const float*)d_in[6];
    const float* f1b   = (const float*)d_in[7];
    const float* fnw   = (const float*)d_in[8];
    const float* fnb   = (const float*)d_in[9];
    float* out = (float*)d_out;
    float* ws  = (float*)d_ws;

    unsigned short* o1b  = (unsigned short*)ws;        // 1152*12800 us = 29.5MB
    unsigned short* out3 = o1b + (size_t)NTOT * 12800; // 3*ASTR bf16
    float* lat  = (float*)(out3 + 3 * ASTR);           // 1024*512
    float* rep  = lat + (size_t)BATCH * 512;           // 128*512
    float* tT   = rep + (size_t)LABEL * 512;           // 512*128
    float* wmat = tT + (size_t)512 * 128;              // 512*512
    float* rho  = wmat + (size_t)512 * 512;            // 1 (+pad)
    unsigned short* Bw3   = (unsigned short*)(rho + 16);   // 3*BSTR bf16
    unsigned short* Bfrag = Bw3 + 3 * BSTR;                // 102,400 bf16
    float* part = (float*)ws;                          // alias o1b (dead after conv2)

    hipLaunchKernelGGL(bprep, dim3(400), dim3(256), 0, stream, c2w, Bfrag);
    hipLaunchKernelGGL(wprep, dim3(6272), dim3(256), 0, stream, f1w, Bw3);
    hipLaunchKernelGGL(conv1_pool, dim3(NTOT), dim3(256), 0, stream, image, limg, c1w, c1b, o1b);
    hipLaunchKernelGGL(conv2_mfma, dim3(NTOT), dim3(256), 0, stream, o1b, Bfrag, c2b, out3);
    hipLaunchKernelGGL(fc1_mfma, dim3(NTOT / 64, 512 / 64, 7), dim3(256), 0, stream,
                       out3, Bw3, part);
    hipLaunchKernelGGL(fc1_reduce, dim3(NTOT * 512 / 256), dim3(256), 0, stream,
                       part, f1b, lat, rep);
    hipLaunchKernelGGL(fcn_softmax, dim3(BATCH), dim3(128), 0, stream, lat, fnw, fnb,
                       out + (size_t)BATCH * LABEL);
    hipLaunchKernelGGL(rho_kernel, dim3(1), dim3(256), 0, stream, rep, rho);
    hipLaunchKernelGGL(t_kernel, dim3(256), dim3(256), 0, stream, rep, rho, tT);
    hipLaunchKernelGGL(w_kernel, dim3(1024), dim3(256), 0, stream, tT, wmat);
    hipLaunchKernelGGL(clustering, dim3(BATCH / CB), dim3(256), 0, stream, lat, wmat, rep, out);
}

// Round 14
// 422.840 us; speedup vs baseline: 1.1998x; 1.0078x over previous
//
#include <hip/hip_runtime.h>
#include <hip/hip_bf16.h>
#include <math.h>

#define BATCH 1024
#define LABEL 128
#define LATENT 512
#define NTOT 1152  // 1024 + 128

typedef short short8 __attribute__((ext_vector_type(8)));
typedef float f32x16 __attribute__((ext_vector_type(16)));

__device__ __forceinline__ unsigned short f2bf(float f) {
    __hip_bfloat16 h = __float2bfloat16(f);
    return *(unsigned short*)&h;
}
__device__ __forceinline__ float bf2f(unsigned short u) {
    __hip_bfloat16 h; *(unsigned short*)&h = u;
    return __bfloat162float(h);
}

// conv1 output layout (per image): 2 bf16 planes of 6400 ushorts (12800B each).
// Plane = 196 compact pixels (14x14) x 32ch, granule = 64B, slot-swizzled:
// off = p*32 + (((oc>>3) ^ (p>>1)) & 3)*8 + (oc&7).  Granules 196..199 zeroed
// (conv2's OOB-redirect target).  Image stride = 12800 ushorts.

// ---------------- conv1 (1->32, 5x5 SAME) + relu + 2x2 maxpool ----------------
__global__ __launch_bounds__(256) void conv1_pool(const float* __restrict__ image,
                                                  const float* __restrict__ limg,
                                                  const float* __restrict__ wt,
                                                  const float* __restrict__ bias,
                                                  unsigned short* __restrict__ o1b) {
    const int n = blockIdx.x;
    const float* in = (n < BATCH) ? (image + (size_t)n * 784)
                                  : (limg + (size_t)(n - BATCH) * 784);
    __shared__ float pin[32][32];
    __shared__ float wts[32 * 25];
    const int tid = threadIdx.x;
    unsigned short* ob = o1b + (size_t)n * 12800;
    for (int i = tid; i < 256; i += 256) {            // zero spare granules
        int pl_ = i >> 7, r = i & 127;
        ob[pl_ * 6400 + 6272 + r] = 0;
    }
    for (int idx = tid; idx < 32 * 32; idx += 256) ((float*)pin)[idx] = 0.f;
    __syncthreads();
    for (int idx = tid; idx < 784; idx += 256) {
        int y = idx / 28, x = idx % 28;
        pin[y + 2][x + 2] = in[idx];
    }
    for (int idx = tid; idx < 800; idx += 256) wts[idx] = wt[idx];
    __syncthreads();
    const int oc = tid & 31;
    float wk[25];
    #pragma unroll
    for (int k = 0; k < 25; ++k) wk[k] = wts[oc * 25 + k];
    float b = bias[oc];
    const int slot_lo = (oc & 7);
    const int gq = oc >> 3;
    for (int o = tid; o < 6272; o += 256) {
        int p = o >> 5, py = p / 14, px = p % 14;
        float win[6][6];
        #pragma unroll
        for (int r = 0; r < 6; ++r)
        #pragma unroll
        for (int c = 0; c < 6; ++c)
            win[r][c] = pin[2 * py + r][2 * px + c];
        float a00 = b, a01 = b, a10 = b, a11 = b;
        #pragma unroll
        for (int ky = 0; ky < 5; ++ky)
        #pragma unroll
        for (int kx = 0; kx < 5; ++kx) {
            float w = wk[ky * 5 + kx];
            a00 = fmaf(win[ky][kx], w, a00);
            a01 = fmaf(win[ky][kx + 1], w, a01);
            a10 = fmaf(win[ky + 1][kx], w, a10);
            a11 = fmaf(win[ky + 1][kx + 1], w, a11);
        }
        float v = fmaxf(fmaxf(fmaxf(a00, a01), fmaxf(a10, a11)), 0.f);
        unsigned short b1 = f2bf(v); float r1 = v - bf2f(b1);
        unsigned short b2 = f2bf(r1);
        int off = p * 32 + (((gq ^ (p >> 1)) & 3) << 3) + slot_lo;
        ob[off] = b1; ob[6400 + off] = b2;
    }
}

// ---------------- merged prep: conv2 B-frags (bf16x2) + f1w planes (bf16x2) ---
#define BSTR ((size_t)512 * 3136)
#define ASTR ((size_t)NTOT * 3136)
__global__ __launch_bounds__(256) void prep(const float* __restrict__ c2w,
                                            const float* __restrict__ f1w,
                                            unsigned short* __restrict__ Bf,
                                            unsigned short* __restrict__ Bw2) {
    int idx = blockIdx.x * 256 + threadIdx.x;
    if (idx < 102400) {              // conv2 B fragments
        int j = idx & 7, lane = (idx >> 3) & 63, ocT = (idx >> 9) & 1, s = idx >> 10;
        int q = lane >> 5, nn = lane & 31;
        int k = 16 * s + 8 * q + j;
        int tap = k >> 5, ic = k & 31;
        int oc = 32 * ocT + nn;
        float v = c2w[oc * 800 + ic * 25 + tap];
        unsigned short b1 = f2bf(v);
        unsigned short b2 = f2bf(v - bf2f(b1));
        size_t base = ((size_t)(s * 2 + ocT) * 2) * 512 + lane * 8 + j;
        Bf[base] = b1; Bf[base + 512] = b2;
        return;
    }
    int i2 = idx - 102400;           // f1w bf16x2 planes
    if (i2 >= 512 * 3136) return;
    float v = f1w[i2];
    unsigned short b1 = f2bf(v);
    unsigned short b2 = f2bf(v - bf2f(b1));
    Bw2[i2] = b1; Bw2[BSTR + i2] = b2;
}

// ---------------- conv2 via MFMA, v7 (r13 proven) + 2-plane output ------------
__global__ __launch_bounds__(256) void conv2_mfma(const unsigned short* __restrict__ o1b,
                                                  const unsigned short* __restrict__ Bf,
                                                  const float* __restrict__ bias,
                                                  unsigned short* __restrict__ out2) {
    const int n = blockIdx.x;
    __shared__ __align__(16) unsigned short pl[12800];   // 25,600B
    const int tid = threadIdx.x;
    const int lane = tid & 63, wv = tid >> 6;
    const int ocT = wv & 1, mh = wv >> 1;

    {
        const float4* src = (const float4*)(o1b + (size_t)n * 12800);
        float4* dst = (float4*)pl;
        for (int i = tid; i < 1600; i += 256) dst[i] = src[i];
    }
    __syncthreads();

    const int m_ = lane & 31, q = lane >> 5;
    int ym[4], xm[4], mm[4], tvv[4];
    #pragma unroll
    for (int tt = 0; tt < 4; ++tt) {
        int t = 4 * mh + tt;            // mh=0: 0..3, mh=1: 4..7 (t=7 dead)
        tvv[tt] = (t < 7);
        int m = 32 * t + m_;
        mm[tt] = m;
        ym[tt] = m / 14;
        xm[tt] = m - 14 * ym[tt];
    }
    f32x16 acc[4];
    {
        float bs = bias[32 * ocT + m_];
        #pragma unroll
        for (int tt = 0; tt < 4; ++tt)
        #pragma unroll
        for (int r = 0; r < 16; ++r) acc[tt][r] = bs;
    }

    for (int s = 0; s < 50; ++s) {
        const unsigned short* bp = Bf + ((size_t)(s * 2 + ocT) * 2) * 512 + lane * 8;
        short8 b1 = *(const short8*)(bp);
        short8 b2 = *(const short8*)(bp + 512);
        int kb = 16 * s + 8 * q;
        int tap = kb >> 5, ic0 = kb & 31, g = ic0 >> 3;
        int ky = (tap * 13) >> 6;       // exact /5 for tap<25
        int kx = tap - ky * 5;
        int iyk = ky - 2, ixk = kx - 2;
        int pq2 = iyk * 14 + ixk;
        short8 a1[4], a2[4];
        #pragma unroll
        for (int tt = 0; tt < 4; ++tt) {
            int iy = ym[tt] + iyk, ix = xm[tt] + ixk;
            int valid = tvv[tt] & ((unsigned)iy < 14u) & ((unsigned)ix < 14u);
            int cpt = valid ? (mm[tt] + pq2) : 196;
            int addr = cpt * 32 + (((g ^ (cpt >> 1)) & 3) << 3);
            a1[tt] = *(const short8*)(pl + addr);
            a2[tt] = *(const short8*)(pl + 6400 + addr);
        }
        #pragma unroll
        for (int tt = 0; tt < 4; ++tt)
            acc[tt] = __builtin_amdgcn_mfma_f32_32x32x16_bf16(a1[tt], b1, acc[tt], 0, 0, 0);
        #pragma unroll
        for (int tt = 0; tt < 4; ++tt)
            acc[tt] = __builtin_amdgcn_mfma_f32_32x32x16_bf16(a1[tt], b2, acc[tt], 0, 0, 0);
        #pragma unroll
        for (int tt = 0; tt < 4; ++tt)
            acc[tt] = __builtin_amdgcn_mfma_f32_32x32x16_bf16(a2[tt], b1, acc[tt], 0, 0, 0);
    }
    __syncthreads();   // planes dead

    // ---- x-pool in-lane -> hx[y][px][oc], stride 65 ----
    float* hx = (float*)pl;
    {
        const int oc = 32 * ocT + m_;
        #pragma unroll
        for (int tt = 0; tt < 4; ++tt)
        #pragma unroll
        for (int e = 0; e < 8; ++e) {
            const int reg = 2 * e;
            const int r = (reg & 3) + 8 * (reg >> 2) + 4 * q;
            const int m = 32 * (4 * mh + tt) + r;
            if (m < 196) {
                float xm2 = fmaxf(acc[tt][reg], acc[tt][reg + 1]);
                int y = (m * 2341) >> 15;        // /14
                int px = (m - 14 * y) >> 1;
                hx[(y * 7 + px) * 65 + oc] = xm2;
            }
        }
    }
    __syncthreads();

    // ---- y-pool + relu + bf16x2 store ----
    for (int idx = tid; idx < 3136; idx += 256) {
        int oc2 = (idx * 2675) >> 17;        // /49
        int p = idx - 49 * oc2;
        int py = (p * 9363) >> 16;           // /7
        int px = p - 7 * py;
        float v = fmaxf(hx[(2 * py * 7 + px) * 65 + oc2],
                        hx[((2 * py + 1) * 7 + px) * 65 + oc2]);
        v = fmaxf(v, 0.f);
        unsigned short b1 = f2bf(v);
        unsigned short b2 = f2bf(v - bf2f(b1));
        size_t o = (size_t)n * 3136 + idx;
        out2[o] = b1; out2[ASTR + o] = b2;
    }
}

// ---------------- fc1 via MFMA, bf16x2 / 3 products, split-K=7 ----------------
__global__ __launch_bounds__(256) void fc1_mfma(const unsigned short* __restrict__ A2,
                                                const unsigned short* __restrict__ B2,
                                                float* __restrict__ part) {
    __shared__ unsigned short As[2][2048];
    __shared__ unsigned short Bs[2][2048];
    const int tid = threadIdx.x;
    const int n0 = blockIdx.x * 64, m0 = blockIdx.y * 64;
    const int koff = blockIdx.z * 448;
    const int lr = tid >> 2, g = tid & 3;
    const int slot = (((g ^ (lr >> 1)) & 3) << 3);
    const int lane = tid & 63, wv = tid >> 6;
    const int nq = wv & 1, mq = wv >> 1;
    const int q = lane >> 5, l31 = lane & 31;
    const int rA = 32 * nq + l31, rB = 32 * mq + l31;
    f32x16 acc;
    #pragma unroll
    for (int r = 0; r < 16; ++r) acc[r] = 0.f;

    for (int bk = 0; bk < 448; bk += 32) {
        const size_t ka = (size_t)(koff + bk + (g << 3));
        short8 av[2], bv[2];
        #pragma unroll
        for (int p = 0; p < 2; ++p) {
            av[p] = *(const short8*)(A2 + p * ASTR + (size_t)(n0 + lr) * 3136 + ka);
            bv[p] = *(const short8*)(B2 + p * BSTR + (size_t)(m0 + lr) * 3136 + ka);
        }
        __syncthreads();
        #pragma unroll
        for (int p = 0; p < 2; ++p) {
            *(short8*)&As[p][(lr << 5) + slot] = av[p];
            *(short8*)&Bs[p][(lr << 5) + slot] = bv[p];
        }
        __syncthreads();
        #pragma unroll
        for (int s2 = 0; s2 < 32; s2 += 16) {
            const int gg = (s2 + (q << 3)) >> 3;
            const int sa = (((gg ^ (rA >> 1)) & 3) << 3);
            const int sb = (((gg ^ (rB >> 1)) & 3) << 3);
            short8 a1 = *(const short8*)&As[0][(rA << 5) + sa];
            short8 a2 = *(const short8*)&As[1][(rA << 5) + sa];
            short8 b1 = *(const short8*)&Bs[0][(rB << 5) + sb];
            short8 b2 = *(const short8*)&Bs[1][(rB << 5) + sb];
            acc = __builtin_amdgcn_mfma_f32_32x32x16_bf16(a1, b1, acc, 0, 0, 0);
            acc = __builtin_amdgcn_mfma_f32_32x32x16_bf16(a1, b2, acc, 0, 0, 0);
            acc = __builtin_amdgcn_mfma_f32_32x32x16_bf16(a2, b1, acc, 0, 0, 0);
        }
    }
    float* pb = part + (size_t)blockIdx.z * NTOT * 512;
    #pragma unroll
    for (int reg = 0; reg < 16; ++reg) {
        int nn = n0 + 32 * nq + (reg & 3) + 8 * (reg >> 2) + 4 * q;
        int mmo = m0 + 32 * mq + l31;
        pb[(size_t)nn * 512 + mmo] = acc[reg];
    }
}

__global__ __launch_bounds__(256) void fc1_reduce(const float* __restrict__ part,
                                                  const float* __restrict__ bias,
                                                  float* __restrict__ lat,
                                                  float* __restrict__ rep) {
    int idx = blockIdx.x * 256 + threadIdx.x;
    int m = idx & 511;
    float v = bias[m];
    #pragma unroll
    for (int kz = 0; kz < 7; ++kz) v += part[(size_t)kz * NTOT * 512 + idx];
    if (idx < BATCH * 512) lat[idx] = v;
    else rep[idx - BATCH * 512] = tanhf(v);
}

// ---------------- label = softmax(lat @ fcn_w.T + fcn_b) ----------------
__global__ __launch_bounds__(128) void fcn_softmax(const float* __restrict__ lat,
                                                   const float* __restrict__ fw,
                                                   const float* __restrict__ fb,
                                                   float* __restrict__ out) {
    const int b = blockIdx.x;
    const int j = threadIdx.x;
    __shared__ float lrow[512];
    __shared__ float red[128];
    for (int i = j; i < 512; i += 128) lrow[i] = lat[b * 512 + i];
    __syncthreads();
    const float4* w4 = (const float4*)(fw + j * 512);
    float acc = fb[j];
    #pragma unroll 4
    for (int qq = 0; qq < 128; ++qq) {
        float4 a = ((const float4*)lrow)[qq];
        float4 w = w4[qq];
        acc += a.x * w.x + a.y * w.y + a.z * w.z + a.w * w.w;
    }
    red[j] = acc;
    __syncthreads();
    for (int off = 64; off >= 1; off >>= 1) {
        if (j < off) red[j] = fmaxf(red[j], red[j + off]);
        __syncthreads();
    }
    float mx = red[0];
    __syncthreads();
    float ex = expf(acc - mx);
    red[j] = ex;
    __syncthreads();
    for (int off = 64; off >= 1; off >>= 1) {
        if (j < off) red[j] += red[j + off];
        __syncthreads();
    }
    out[b * 128 + j] = ex / red[0];
}

// ---------------- rho / t / w ----------------
__global__ __launch_bounds__(256) void rho_kernel(const float* __restrict__ rep,
                                                  float* __restrict__ rho) {
    __shared__ float red[256];
    const int tid = threadIdx.x;
    float s = 0.f;
    for (int i = tid; i < LABEL * LATENT; i += 256) s += rep[i];
    red[tid] = s;
    __syncthreads();
    for (int off = 128; off >= 1; off >>= 1) {
        if (tid < off) red[tid] += red[tid + off];
        __syncthreads();
    }
    if (tid == 0) rho[0] = red[0] / (float)(LABEL * LATENT);
}

__global__ __launch_bounds__(256) void t_kernel(const float* __restrict__ rep,
                                                const float* __restrict__ rho,
                                                float* __restrict__ tT) {
    int idx = blockIdx.x * 256 + threadIdx.x;
    int i = idx / 128, k = idx % 128;
    tT[idx] = rep[k * 512 + i] - rho[0];
}

__global__ __launch_bounds__(256) void w_kernel(const float* __restrict__ tT,
                                                float* __restrict__ w) {
    int idx = blockIdx.x * 256 + threadIdx.x;
    int i = idx >> 9, j = idx & 511;
    const float4* a = (const float4*)(tT + i * 128);
    const float4* b = (const float4*)(tT + j * 128);
    float acc = 0.f;
    #pragma unroll 8
    for (int q = 0; q < 32; ++q) {
        float4 av = a[q], bv = b[q];
        acc += av.x * bv.x + av.y * bv.y + av.z * bv.z + av.w * bv.w;
    }
    w[idx] = (i == j) ? 0.f : acc * (1.f / 128.f);
}

// ---------------- hinit: hmat = tanh(lat) @ w  (fp32 tiled GEMM) --------------
// Replaces the per-clustering-block 1MB serial w sweep (512 blocks x 1MB L2
// traffic on a dependent chain) with one 128-block GEMM with full w reuse.
// w symmetric: C[n][m] = sum_k s[n][k] w[m][k] == (s @ w)[n][m].
__global__ __launch_bounds__(256) void hinit(const float* __restrict__ lat,
                                             const float* __restrict__ w,
                                             float* __restrict__ hmat) {
    __shared__ float As[16][68];
    __shared__ float Bs[16][68];
    const int tid = threadIdx.x;
    const int n0 = blockIdx.x * 64, m0 = blockIdx.y * 64;
    const int lr = tid >> 2;
    const int lk = (tid & 3) * 4;
    const int ty = tid >> 4, tx = tid & 15;
    float c[4][4] = {};
    for (int k0 = 0; k0 < 512; k0 += 16) {
        float4 a4 = *(const float4*)(lat + (size_t)(n0 + lr) * 512 + k0 + lk);
        float4 b4 = *(const float4*)(w + (size_t)(m0 + lr) * 512 + k0 + lk);
        a4.x = tanhf(a4.x); a4.y = tanhf(a4.y); a4.z = tanhf(a4.z); a4.w = tanhf(a4.w);
        __syncthreads();
        As[lk + 0][lr] = a4.x; As[lk + 1][lr] = a4.y; As[lk + 2][lr] = a4.z; As[lk + 3][lr] = a4.w;
        Bs[lk + 0][lr] = b4.x; Bs[lk + 1][lr] = b4.y; Bs[lk + 2][lr] = b4.z; Bs[lk + 3][lr] = b4.w;
        __syncthreads();
        #pragma unroll
        for (int kk = 0; kk < 16; ++kk) {
            float av[4], bv[4];
            #pragma unroll
            for (int i = 0; i < 4; ++i) av[i] = As[kk][ty * 4 + i];
            #pragma unroll
            for (int j = 0; j < 4; ++j) bv[j] = Bs[kk][tx * 4 + j];
            #pragma unroll
            for (int i = 0; i < 4; ++i)
            #pragma unroll
            for (int j = 0; j < 4; ++j) c[i][j] += av[i] * bv[j];
        }
    }
    #pragma unroll
    for (int i = 0; i < 4; ++i)
    #pragma unroll
    for (int j = 0; j < 4; ++j)
        hmat[(size_t)(n0 + ty * 4 + i) * 512 + m0 + tx * 4 + j] = c[i][j];
}

// ---------------- clustering: incremental Hopfield, h0 precomputed ------------
#define CB 2
__device__ __forceinline__ float sgnf(float x) {
    return (x > 0.f) ? 1.f : ((x < 0.f) ? -1.f : 0.f);
}

__global__ __launch_bounds__(256) void clustering(const float* __restrict__ lat,
                                                  const float* __restrict__ hmat,
                                                  const float* __restrict__ w,
                                                  const float* __restrict__ rep,
                                                  float* __restrict__ out) {
    const int tid = threadIdx.x;
    const int row0 = blockIdx.x * CB;
    __shared__ float mins[CB][512];
    __shared__ float red[256];
    __shared__ float part_e[4][CB];
    __shared__ int part_c[4];
    __shared__ float min_e[CB];
    __shared__ int copyf[CB];
    __shared__ int donef[CB];
    __shared__ int cnt[CB];
    __shared__ int jidx[CB][512];
    __shared__ float jdel[CB][512];
    const int i0 = 2 * tid, i1 = 2 * tid + 1;
    const int wave = tid >> 6, lane = tid & 63;

    float sm10[CB], sm11[CB], sm20[CB], sm21[CB], h0[CB], h1[CB];
    #pragma unroll
    for (int r = 0; r < CB; ++r) {
        float a = tanhf(lat[(row0 + r) * 512 + i0]);
        float b = tanhf(lat[(row0 + r) * 512 + i1]);
        sm10[r] = a; sm11[r] = b;
        sm20[r] = a; sm21[r] = b;
        h0[r] = hmat[(size_t)(row0 + r) * 512 + i0];
        h1[r] = hmat[(size_t)(row0 + r) * 512 + i1];
    }
    if (tid < CB) { min_e[tid] = INFINITY; donef[tid] = 0; cnt[tid] = 0; }
    __syncthreads();

    for (int k = 1; k <= 512; ++k) {
        float sn0[CB], sn1[CB];
        int cy = (1 << CB) - 1;
        #pragma unroll
        for (int r = 0; r < CB; ++r) {
            int dn = donef[r];
            if (dn) {
                sn0[r] = sm10[r]; sn1[r] = sm11[r];
            } else {
                sn0[r] = fabsf(sm10[r]) * sgnf(h0[r]);
                sn1[r] = fabsf(sm11[r]) * sgnf(h1[r]);
                if (!(sn0[r] == sm20[r] && sn1[r] == sm21[r])) cy &= ~(1 << r);
                if (sn0[r] != sm10[r]) {
                    int p = atomicAdd(&cnt[r], 1);
                    jidx[r][p] = i0; jdel[r][p] = sn0[r] - sm10[r];
                }
                if (sn1[r] != sm11[r]) {
                    int p = atomicAdd(&cnt[r], 1);
                    jidx[r][p] = i1; jdel[r][p] = sn1[r] - sm11[r];
                }
            }
        }
        #pragma unroll
        for (int m = 32; m >= 1; m >>= 1) cy &= __shfl_xor(cy, m, 64);
        if (lane == 0) part_c[wave] = cy;
        __syncthreads();

        #pragma unroll
        for (int r = 0; r < CB; ++r) {
            const int c = cnt[r];
            #pragma unroll 4
            for (int t = 0; t < c; ++t) {
                const int j = jidx[r][t];
                const float d = jdel[r][t];
                const float2 wvv = *(const float2*)(w + (size_t)j * 512 + i0);
                h0[r] = fmaf(d, wvv.x, h0[r]);
                h1[r] = fmaf(d, wvv.y, h1[r]);
            }
        }
        float ep[CB];
        #pragma unroll
        for (int r = 0; r < CB; ++r) ep[r] = sn0[r] * h0[r] + sn1[r] * h1[r];
        #pragma unroll
        for (int m = 32; m >= 1; m >>= 1) {
            #pragma unroll
            for (int r = 0; r < CB; ++r) ep[r] += __shfl_xor(ep[r], m, 64);
        }
        if (lane == 0) {
            #pragma unroll
            for (int r = 0; r < CB; ++r) part_e[wave][r] = ep[r];
        }
        __syncthreads();

        if (tid < CB) {
            int r = tid;
            if (!donef[r]) {
                float e = -(part_e[0][r] + part_e[1][r] + part_e[2][r] + part_e[3][r]);
                int better = e < min_e[r];
                if (better) min_e[r] = e;
                copyf[r] = better;
                int fl = part_c[0] & part_c[1] & part_c[2] & part_c[3];
                int fixedp = (cnt[r] == 0);
                int cyc = (k >= 2) && ((fl >> r) & 1);
                if (fixedp || cyc) donef[r] = 1;
            } else {
                copyf[r] = 0;
            }
            cnt[r] = 0;
        }
        __syncthreads();

        int alldone = 1;
        #pragma unroll
        for (int r = 0; r < CB; ++r) {
            if (copyf[r]) { mins[r][i0] = sn0[r]; mins[r][i1] = sn1[r]; }
            alldone &= donef[r];
            sm20[r] = sm10[r]; sm21[r] = sm11[r];
            sm10[r] = sn0[r];  sm11[r] = sn1[r];
        }
        if (alldone) break;
    }
    __syncthreads();

    const int j = tid & 127, half = tid >> 7;
    for (int r = 0; r < CB; ++r) {
        const float4* rr = (const float4*)(rep + (size_t)j * 512 + half * 256);
        const float4* ms = (const float4*)(&mins[r][half * 256]);
        float p = 0.f;
        #pragma unroll 8
        for (int q = 0; q < 64; ++q) {
            float4 rv = rr[q], mv = ms[q];
            p += rv.x * mv.x + rv.y * mv.y + rv.z * mv.z + rv.w * mv.w;
        }
        red[tid] = p;
        __syncthreads();
        float v = 0.f;
        if (tid < 128) { v = fabsf(red[tid] + red[tid + 128]); red[tid] = v; }
        __syncthreads();
        for (int off = 64; off >= 1; off >>= 1) {
            if (tid < off) red[tid] = fmaxf(red[tid], red[tid + off]);
            __syncthreads();
        }
        float mx = red[0];
        __syncthreads();
        float ex = 0.f;
        if (tid < 128) { ex = expf(v - mx); red[tid] = ex; }
        __syncthreads();
        for (int off = 64; off >= 1; off >>= 1) {
            if (tid < off) red[tid] += red[tid + off];
            __syncthreads();
        }
        if (tid < 128) out[(size_t)(row0 + r) * 128 + tid] = ex / red[0];
        __syncthreads();
    }
}

extern "C" void kernel_launch(void* const* d_in, const int* in_sizes, int n_in,
                              void* d_out, int out_size, void* d_ws, size_t ws_size,
                              hipStream_t stream) {
    const float* image = (const float*)d_in[0];
    const float* limg  = (const float*)d_in[1];
    const float* c1w   = (const float*)d_in[2];
    const float* c1b   = (const float*)d_in[3];
    const float* c2w   = (const float*)d_in[4];
    const float* c2b   = (const float*)d_in[5];
    const float* f1w   = (const float*)d_in[6];
    const float* f1b   = (const float*)d_in[7];
    const float* fnw   = (const float*)d_in[8];
    const float* fnb   = (const float*)d_in[9];
    float* out = (float*)d_out;
    float* ws  = (float*)d_ws;

    unsigned short* o1b  = (unsigned short*)ws;        // 1152*12800 us = 29.5MB
    unsigned short* out2 = o1b + (size_t)NTOT * 12800; // 2*ASTR bf16 = 14.5MB
    float* lat  = (float*)(out2 + 2 * ASTR);           // 1024*512
    float* rep  = lat + (size_t)BATCH * 512;           // 128*512
    float* tT   = rep + (size_t)LABEL * 512;           // 512*128
    float* wmat = tT + (size_t)512 * 128;              // 512*512
    float* rho  = wmat + (size_t)512 * 512;            // 1 (+pad)
    unsigned short* Bw2   = (unsigned short*)(rho + 16);   // 2*BSTR bf16
    unsigned short* Bfrag = Bw2 + 2 * BSTR;                // 102,400 bf16
    float* hmat = (float*)(Bfrag + 102400);            // 1024*512 f32 = 2MB
    float* part = (float*)ws;                          // alias o1b (dead after conv2)

    hipLaunchKernelGGL(prep, dim3((102400 + 512 * 3136 + 255) / 256), dim3(256), 0, stream,
                       c2w, f1w, Bfrag, Bw2);
    hipLaunchKernelGGL(conv1_pool, dim3(NTOT), dim3(256), 0, stream, image, limg, c1w, c1b, o1b);
    hipLaunchKernelGGL(conv2_mfma, dim3(NTOT), dim3(256), 0, stream, o1b, Bfrag, c2b, out2);
    hipLaunchKernelGGL(fc1_mfma, dim3(NTOT / 64, 512 / 64, 7), dim3(256), 0, stream,
                       out2, Bw2, part);
    hipLaunchKernelGGL(fc1_reduce, dim3(NTOT * 512 / 256), dim3(256), 0, stream,
                       part, f1b, lat, rep);
    hipLaunchKernelGGL(fcn_softmax, dim3(BATCH), dim3(128), 0, stream, lat, fnw, fnb,
                       out + (size_t)BATCH * LABEL);
    hipLaunchKernelGGL(rho_kernel, dim3(1), dim3(256), 0, stream, rep, rho);
    hipLaunchKernelGGL(t_kernel, dim3(256), dim3(256), 0, stream, rep, rho, tT);
    hipLaunchKernelGGL(w_kernel, dim3(1024), dim3(256), 0, stream, tT, wmat);
    hipLaunchKernelGGL(hinit, dim3(BATCH / 64, 512 / 64), dim3(256), 0, stream, lat, wmat, hmat);
    hipLaunchKernelGGL(clustering, dim3(BATCH / CB), dim3(256), 0, stream,
                       lat, hmat, wmat, rep, out);
}

// Round 17
// 401.214 us; speedup vs baseline: 1.2645x; 1.0539x over previous
//
#include <hip/hip_runtime.h>
#include <hip/hip_bf16.h>
#include <math.h>

#define BATCH 1024
#define LABEL 128
#define LATENT 512
#define NTOT 1152  // 1024 + 128

typedef short short8 __attribute__((ext_vector_type(8)));
typedef float f32x16 __attribute__((ext_vector_type(16)));

__device__ __forceinline__ unsigned short f2bf(float f) {
    __hip_bfloat16 h = __float2bfloat16(f);
    return *(unsigned short*)&h;
}
__device__ __forceinline__ float bf2f(unsigned short u) {
    __hip_bfloat16 h; *(unsigned short*)&h = u;
    return __bfloat162float(h);
}

#define BSTR ((size_t)512 * 3136)
#define ASTR ((size_t)NTOT * 3136)
#define A2STR ((size_t)BATCH * 512)
#define W2STR ((size_t)LABEL * 512)

// conv1 output layout (per image): 2 bf16 planes of 6400 ushorts.
// Plane = 196 compact pixels (14x14) x 32ch, granule = 64B, slot-swizzled:
// off = p*32 + (((oc>>3) ^ (p>>1)) & 3)*8 + (oc&7).  Granules 196..199 zeroed.
//
// NUMERICS RULE (r15): w_kernel/t/rho keep r14-exact op order (Hopfield sign
// cascades). COVERAGE RULE (r16): conv1 v2 only wrote px 0..6 -- half the
// pixels stayed 0xAA poison; v3 adds the xh column-half loop.

// ------- conv1 v3: register sliding window over BOTH column halves ------------
__global__ __launch_bounds__(256) void conv1_pool(const float* __restrict__ image,
                                                  const float* __restrict__ limg,
                                                  const float* __restrict__ wt,
                                                  const float* __restrict__ bias,
                                                  unsigned short* __restrict__ o1b) {
    const int n = blockIdx.x;
    const float* in = (n < BATCH) ? (image + (size_t)n * 784)
                                  : (limg + (size_t)(n - BATCH) * 784);
    __shared__ float pin[32][32];
    __shared__ float wts[32 * 25];
    const int tid = threadIdx.x;
    unsigned short* ob = o1b + (size_t)n * 12800;
    for (int i = tid; i < 256; i += 256) {
        int pl_ = i >> 7, r = i & 127;
        ob[pl_ * 6400 + 6272 + r] = 0;
    }
    for (int idx = tid; idx < 32 * 32; idx += 256) ((float*)pin)[idx] = 0.f;
    __syncthreads();
    for (int idx = tid; idx < 784; idx += 256) {
        int y = idx / 28, x = idx % 28;
        pin[y + 2][x + 2] = in[idx];
    }
    for (int idx = tid; idx < 800; idx += 256) wts[idx] = wt[idx];
    __syncthreads();
    const int oc = tid & 31;
    float wk[25];
    #pragma unroll
    for (int k = 0; k < 25; ++k) wk[k] = wts[oc * 25 + k];
    const float b = bias[oc];
    const int slot_lo = (oc & 7);
    const int gq = oc >> 3;
    for (int it = 0; it < 2; ++it) {
        const int py = (tid >> 5) + it * 8;
        if (py >= 14) continue;
        #pragma unroll
        for (int xh = 0; xh < 2; ++xh) {
            const int acol = xh ? 12 : 0;   // aligned float4 start column
            const int off = xh ? 2 : 0;     // conv col 14*xh + c = pin col acol+c+off
            float a0[14], a1[14];
            #pragma unroll
            for (int c = 0; c < 14; ++c) { a0[c] = b; a1[c] = b; }
            #pragma unroll
            for (int t = 0; t < 6; ++t) {
                float row[20];
                const float4* rp = (const float4*)&pin[2 * py + t][acol];
                #pragma unroll
                for (int v = 0; v < 5; ++v) {
                    float4 f = rp[v];
                    row[4 * v] = f.x; row[4 * v + 1] = f.y;
                    row[4 * v + 2] = f.z; row[4 * v + 3] = f.w;
                }
                if (t < 5) {
                    #pragma unroll
                    for (int kx = 0; kx < 5; ++kx) {
                        float w0 = wk[t * 5 + kx];
                        #pragma unroll
                        for (int c = 0; c < 14; ++c)
                            a0[c] = fmaf(row[c + kx + off], w0, a0[c]);
                    }
                }
                if (t >= 1) {
                    #pragma unroll
                    for (int kx = 0; kx < 5; ++kx) {
                        float w1 = wk[(t - 1) * 5 + kx];
                        #pragma unroll
                        for (int c = 0; c < 14; ++c)
                            a1[c] = fmaf(row[c + kx + off], w1, a1[c]);
                    }
                }
            }
            #pragma unroll
            for (int px = 0; px < 7; ++px) {
                float v = fmaxf(fmaxf(a0[2 * px], a0[2 * px + 1]),
                                fmaxf(a1[2 * px], a1[2 * px + 1]));
                v = fmaxf(v, 0.f);
                unsigned short b1 = f2bf(v);
                unsigned short b2 = f2bf(v - bf2f(b1));
                int p = py * 14 + 7 * xh + px;
                int offo = p * 32 + (((gq ^ (p >> 1)) & 3) << 3) + slot_lo;
                ob[offo] = b1; ob[6400 + offo] = b2;
            }
        }
    }
}

// ------- merged prep: conv2 B-frags + f1w planes + fnw planes (all bf16x2) ----
__global__ __launch_bounds__(256) void prep(const float* __restrict__ c2w,
                                            const float* __restrict__ f1w,
                                            const float* __restrict__ fnw,
                                            unsigned short* __restrict__ Bf,
                                            unsigned short* __restrict__ Bw2,
                                            unsigned short* __restrict__ Bn2) {
    int idx = blockIdx.x * 256 + threadIdx.x;
    if (idx < 102400) {              // conv2 B fragments
        int j = idx & 7, lane = (idx >> 3) & 63, ocT = (idx >> 9) & 1, s = idx >> 10;
        int q = lane >> 5, nn = lane & 31;
        int k = 16 * s + 8 * q + j;
        int tap = k >> 5, ic = k & 31;
        int oc = 32 * ocT + nn;
        float v = c2w[oc * 800 + ic * 25 + tap];
        unsigned short b1 = f2bf(v);
        unsigned short b2 = f2bf(v - bf2f(b1));
        size_t base = ((size_t)(s * 2 + ocT) * 2) * 512 + lane * 8 + j;
        Bf[base] = b1; Bf[base + 512] = b2;
        return;
    }
    int i2 = idx - 102400;
    if (i2 < 512 * 3136) {           // f1w bf16x2 planes
        float v = f1w[i2];
        unsigned short b1 = f2bf(v);
        unsigned short b2 = f2bf(v - bf2f(b1));
        Bw2[i2] = b1; Bw2[BSTR + i2] = b2;
        return;
    }
    int i3 = i2 - 512 * 3136;        // fnw bf16x2 planes
    if (i3 >= 128 * 512) return;
    float v = fnw[i3];
    unsigned short b1 = f2bf(v);
    unsigned short b2 = f2bf(v - bf2f(b1));
    Bn2[i3] = b1; Bn2[W2STR + i3] = b2;
}

// ------- conv2 via MFMA, v7 (r13 proven, unchanged) ---------------------------
__global__ __launch_bounds__(256) void conv2_mfma(const unsigned short* __restrict__ o1b,
                                                  const unsigned short* __restrict__ Bf,
                                                  const float* __restrict__ bias,
                                                  unsigned short* __restrict__ out2) {
    const int n = blockIdx.x;
    __shared__ __align__(16) unsigned short pl[12800];
    const int tid = threadIdx.x;
    const int lane = tid & 63, wv = tid >> 6;
    const int ocT = wv & 1, mh = wv >> 1;

    {
        const float4* src = (const float4*)(o1b + (size_t)n * 12800);
        float4* dst = (float4*)pl;
        for (int i = tid; i < 1600; i += 256) dst[i] = src[i];
    }
    __syncthreads();

    const int m_ = lane & 31, q = lane >> 5;
    int ym[4], xm[4], mm[4], tvv[4];
    #pragma unroll
    for (int tt = 0; tt < 4; ++tt) {
        int t = 4 * mh + tt;
        tvv[tt] = (t < 7);
        int m = 32 * t + m_;
        mm[tt] = m;
        ym[tt] = m / 14;
        xm[tt] = m - 14 * ym[tt];
    }
    f32x16 acc[4];
    {
        float bs = bias[32 * ocT + m_];
        #pragma unroll
        for (int tt = 0; tt < 4; ++tt)
        #pragma unroll
        for (int r = 0; r < 16; ++r) acc[tt][r] = bs;
    }

    for (int s = 0; s < 50; ++s) {
        const unsigned short* bp = Bf + ((size_t)(s * 2 + ocT) * 2) * 512 + lane * 8;
        short8 b1 = *(const short8*)(bp);
        short8 b2 = *(const short8*)(bp + 512);
        int kb = 16 * s + 8 * q;
        int tap = kb >> 5, ic0 = kb & 31, g = ic0 >> 3;
        int ky = (tap * 13) >> 6;
        int kx = tap - ky * 5;
        int iyk = ky - 2, ixk = kx - 2;
        int pq2 = iyk * 14 + ixk;
        short8 a1[4], a2[4];
        #pragma unroll
        for (int tt = 0; tt < 4; ++tt) {
            int iy = ym[tt] + iyk, ix = xm[tt] + ixk;
            int valid = tvv[tt] & ((unsigned)iy < 14u) & ((unsigned)ix < 14u);
            int cpt = valid ? (mm[tt] + pq2) : 196;
            int addr = cpt * 32 + (((g ^ (cpt >> 1)) & 3) << 3);
            a1[tt] = *(const short8*)(pl + addr);
            a2[tt] = *(const short8*)(pl + 6400 + addr);
        }
        #pragma unroll
        for (int tt = 0; tt < 4; ++tt)
            acc[tt] = __builtin_amdgcn_mfma_f32_32x32x16_bf16(a1[tt], b1, acc[tt], 0, 0, 0);
        #pragma unroll
        for (int tt = 0; tt < 4; ++tt)
            acc[tt] = __builtin_amdgcn_mfma_f32_32x32x16_bf16(a1[tt], b2, acc[tt], 0, 0, 0);
        #pragma unroll
        for (int tt = 0; tt < 4; ++tt)
            acc[tt] = __builtin_amdgcn_mfma_f32_32x32x16_bf16(a2[tt], b1, acc[tt], 0, 0, 0);
    }
    __syncthreads();

    float* hx = (float*)pl;
    {
        const int oc = 32 * ocT + m_;
        #pragma unroll
        for (int tt = 0; tt < 4; ++tt)
        #pragma unroll
        for (int e = 0; e < 8; ++e) {
            const int reg = 2 * e;
            const int r = (reg & 3) + 8 * (reg >> 2) + 4 * q;
            const int m = 32 * (4 * mh + tt) + r;
            if (m < 196) {
                float xm2 = fmaxf(acc[tt][reg], acc[tt][reg + 1]);
                int y = (m * 2341) >> 15;
                int px = (m - 14 * y) >> 1;
                hx[(y * 7 + px) * 65 + oc] = xm2;
            }
        }
    }
    __syncthreads();

    for (int idx = tid; idx < 3136; idx += 256) {
        int oc2 = (idx * 2675) >> 17;
        int p = idx - 49 * oc2;
        int py = (p * 9363) >> 16;
        int px = p - 7 * py;
        float v = fmaxf(hx[(2 * py * 7 + px) * 65 + oc2],
                        hx[((2 * py + 1) * 7 + px) * 65 + oc2]);
        v = fmaxf(v, 0.f);
        unsigned short b1 = f2bf(v);
        unsigned short b2 = f2bf(v - bf2f(b1));
        size_t o = (size_t)n * 3136 + idx;
        out2[o] = b1; out2[ASTR + o] = b2;
    }
}

// ------- fc1 via MFMA, bf16x2 / 3 products, split-K=7 (r14 proven) ------------
__global__ __launch_bounds__(256) void fc1_mfma(const unsigned short* __restrict__ A2,
                                                const unsigned short* __restrict__ B2,
                                                float* __restrict__ part) {
    __shared__ unsigned short As[2][2048];
    __shared__ unsigned short Bs[2][2048];
    const int tid = threadIdx.x;
    const int n0 = blockIdx.x * 64, m0 = blockIdx.y * 64;
    const int koff = blockIdx.z * 448;
    const int lr = tid >> 2, g = tid & 3;
    const int slot = (((g ^ (lr >> 1)) & 3) << 3);
    const int lane = tid & 63, wv = tid >> 6;
    const int nq = wv & 1, mq = wv >> 1;
    const int q = lane >> 5, l31 = lane & 31;
    const int rA = 32 * nq + l31, rB = 32 * mq + l31;
    f32x16 acc;
    #pragma unroll
    for (int r = 0; r < 16; ++r) acc[r] = 0.f;

    for (int bk = 0; bk < 448; bk += 32) {
        const size_t ka = (size_t)(koff + bk + (g << 3));
        short8 av[2], bv[2];
        #pragma unroll
        for (int p = 0; p < 2; ++p) {
            av[p] = *(const short8*)(A2 + p * ASTR + (size_t)(n0 + lr) * 3136 + ka);
            bv[p] = *(const short8*)(B2 + p * BSTR + (size_t)(m0 + lr) * 3136 + ka);
        }
        __syncthreads();
        #pragma unroll
        for (int p = 0; p < 2; ++p) {
            *(short8*)&As[p][(lr << 5) + slot] = av[p];
            *(short8*)&Bs[p][(lr << 5) + slot] = bv[p];
        }
        __syncthreads();
        #pragma unroll
        for (int s2 = 0; s2 < 32; s2 += 16) {
            const int gg = (s2 + (q << 3)) >> 3;
            const int sa = (((gg ^ (rA >> 1)) & 3) << 3);
            const int sb = (((gg ^ (rB >> 1)) & 3) << 3);
            short8 a1 = *(const short8*)&As[0][(rA << 5) + sa];
            short8 a2 = *(const short8*)&As[1][(rA << 5) + sa];
            short8 b1 = *(const short8*)&Bs[0][(rB << 5) + sb];
            short8 b2 = *(const short8*)&Bs[1][(rB << 5) + sb];
            acc = __builtin_amdgcn_mfma_f32_32x32x16_bf16(a1, b1, acc, 0, 0, 0);
            acc = __builtin_amdgcn_mfma_f32_32x32x16_bf16(a1, b2, acc, 0, 0, 0);
            acc = __builtin_amdgcn_mfma_f32_32x32x16_bf16(a2, b1, acc, 0, 0, 0);
        }
    }
    float* pb = part + (size_t)blockIdx.z * NTOT * 512;
    #pragma unroll
    for (int reg = 0; reg < 16; ++reg) {
        int nn = n0 + 32 * nq + (reg & 3) + 8 * (reg >> 2) + 4 * q;
        int mmo = m0 + 32 * mq + l31;
        pb[(size_t)nn * 512 + mmo] = acc[reg];
    }
}

__global__ __launch_bounds__(256) void fc1_reduce(const float* __restrict__ part,
                                                  const float* __restrict__ bias,
                                                  float* __restrict__ lat,
                                                  unsigned short* __restrict__ lat2,
                                                  float* __restrict__ rep) {
    int idx = blockIdx.x * 256 + threadIdx.x;
    int m = idx & 511;
    float v = bias[m];
    #pragma unroll
    for (int kz = 0; kz < 7; ++kz) v += part[(size_t)kz * NTOT * 512 + idx];
    if (idx < BATCH * 512) {
        lat[idx] = v;
        unsigned short b1 = f2bf(v);
        lat2[idx] = b1;
        lat2[A2STR + idx] = f2bf(v - bf2f(b1));
    } else {
        rep[idx - BATCH * 512] = tanhf(v);
    }
}

// ------- fcn logits via MFMA (bf16x2 / 3 products), grid (16,2) ---------------
__global__ __launch_bounds__(256) void fcn_mfma(const unsigned short* __restrict__ A2,
                                                const unsigned short* __restrict__ B2,
                                                float* __restrict__ logits) {
    __shared__ unsigned short As[2][2048];
    __shared__ unsigned short Bs[2][2048];
    const int tid = threadIdx.x;
    const int n0 = blockIdx.x * 64, m0 = blockIdx.y * 64;
    const int lr = tid >> 2, g = tid & 3;
    const int slot = (((g ^ (lr >> 1)) & 3) << 3);
    const int lane = tid & 63, wv = tid >> 6;
    const int nq = wv & 1, mq = wv >> 1;
    const int q = lane >> 5, l31 = lane & 31;
    const int rA = 32 * nq + l31, rB = 32 * mq + l31;
    f32x16 acc;
    #pragma unroll
    for (int r = 0; r < 16; ++r) acc[r] = 0.f;

    for (int bk = 0; bk < 512; bk += 32) {
        const size_t ka = (size_t)(bk + (g << 3));
        short8 av[2], bv[2];
        #pragma unroll
        for (int p = 0; p < 2; ++p) {
            av[p] = *(const short8*)(A2 + p * A2STR + (size_t)(n0 + lr) * 512 + ka);
            bv[p] = *(const short8*)(B2 + p * W2STR + (size_t)(m0 + lr) * 512 + ka);
        }
        __syncthreads();
        #pragma unroll
        for (int p = 0; p < 2; ++p) {
            *(short8*)&As[p][(lr << 5) + slot] = av[p];
            *(short8*)&Bs[p][(lr << 5) + slot] = bv[p];
        }
        __syncthreads();
        #pragma unroll
        for (int s2 = 0; s2 < 32; s2 += 16) {
            const int gg = (s2 + (q << 3)) >> 3;
            const int sa = (((gg ^ (rA >> 1)) & 3) << 3);
            const int sb = (((gg ^ (rB >> 1)) & 3) << 3);
            short8 a1 = *(const short8*)&As[0][(rA << 5) + sa];
            short8 a2 = *(const short8*)&As[1][(rA << 5) + sa];
            short8 b1 = *(const short8*)&Bs[0][(rB << 5) + sb];
            short8 b2 = *(const short8*)&Bs[1][(rB << 5) + sb];
            acc = __builtin_amdgcn_mfma_f32_32x32x16_bf16(a1, b1, acc, 0, 0, 0);
            acc = __builtin_amdgcn_mfma_f32_32x32x16_bf16(a1, b2, acc, 0, 0, 0);
            acc = __builtin_amdgcn_mfma_f32_32x32x16_bf16(a2, b1, acc, 0, 0, 0);
        }
    }
    #pragma unroll
    for (int reg = 0; reg < 16; ++reg) {
        int nn = n0 + 32 * nq + (reg & 3) + 8 * (reg >> 2) + 4 * q;
        int mmo = m0 + 32 * mq + l31;
        logits[(size_t)nn * 128 + mmo] = acc[reg];
    }
}

// ------- softmax over 128 logits + bias ---------------------------------------
__global__ __launch_bounds__(128) void fcn_softmax2(const float* __restrict__ logits,
                                                    const float* __restrict__ fb,
                                                    float* __restrict__ out) {
    const int b = blockIdx.x;
    const int j = threadIdx.x;
    __shared__ float red[128];
    float acc = logits[(size_t)b * 128 + j] + fb[j];
    red[j] = acc;
    __syncthreads();
    for (int off = 64; off >= 1; off >>= 1) {
        if (j < off) red[j] = fmaxf(red[j], red[j + off]);
        __syncthreads();
    }
    float mx = red[0];
    __syncthreads();
    float ex = expf(acc - mx);
    red[j] = ex;
    __syncthreads();
    for (int off = 64; off >= 1; off >>= 1) {
        if (j < off) red[j] += red[j + off];
        __syncthreads();
    }
    out[(size_t)b * 128 + j] = ex / red[0];
}

// ------- rho / t (r14-exact, numerics load-bearing) ---------------------------
__global__ __launch_bounds__(256) void rho_kernel(const float* __restrict__ rep,
                                                  float* __restrict__ rho) {
    __shared__ float red[256];
    const int tid = threadIdx.x;
    float s = 0.f;
    for (int i = tid; i < LABEL * LATENT; i += 256) s += rep[i];
    red[tid] = s;
    __syncthreads();
    for (int off = 128; off >= 1; off >>= 1) {
        if (tid < off) red[tid] += red[tid + off];
        __syncthreads();
    }
    if (tid == 0) rho[0] = red[0] / (float)(LABEL * LATENT);
}

__global__ __launch_bounds__(256) void t_kernel(const float* __restrict__ rep,
                                                const float* __restrict__ rho,
                                                float* __restrict__ tT) {
    int idx = blockIdx.x * 256 + threadIdx.x;
    int i = idx / 128, k = idx % 128;
    tT[idx] = rep[k * 512 + i] - rho[0];
}

// ------- w_kernel: r14-EXACT (summation order load-bearing) -------------------
__global__ __launch_bounds__(256) void w_kernel(const float* __restrict__ tT,
                                                float* __restrict__ w) {
    int idx = blockIdx.x * 256 + threadIdx.x;
    int i = idx >> 9, j = idx & 511;
    const float4* a = (const float4*)(tT + i * 128);
    const float4* b = (const float4*)(tT + j * 128);
    float acc = 0.f;
    #pragma unroll 8
    for (int q = 0; q < 32; ++q) {
        float4 av = a[q], bv = b[q];
        acc += av.x * bv.x + av.y * bv.y + av.z * bv.z + av.w * bv.w;
    }
    w[idx] = (i == j) ? 0.f : acc * (1.f / 128.f);
}

// ------- hinit: hmat = tanh(lat) @ w  (r14 proven) ----------------------------
__global__ __launch_bounds__(256) void hinit(const float* __restrict__ lat,
                                             const float* __restrict__ w,
                                             float* __restrict__ hmat) {
    __shared__ float As[16][68];
    __shared__ float Bs[16][68];
    const int tid = threadIdx.x;
    const int n0 = blockIdx.x * 64, m0 = blockIdx.y * 64;
    const int lr = tid >> 2;
    const int lk = (tid & 3) * 4;
    const int ty = tid >> 4, tx = tid & 15;
    float c[4][4] = {};
    for (int k0 = 0; k0 < 512; k0 += 16) {
        float4 a4 = *(const float4*)(lat + (size_t)(n0 + lr) * 512 + k0 + lk);
        float4 b4 = *(const float4*)(w + (size_t)(m0 + lr) * 512 + k0 + lk);
        a4.x = tanhf(a4.x); a4.y = tanhf(a4.y); a4.z = tanhf(a4.z); a4.w = tanhf(a4.w);
        __syncthreads();
        As[lk + 0][lr] = a4.x; As[lk + 1][lr] = a4.y; As[lk + 2][lr] = a4.z; As[lk + 3][lr] = a4.w;
        Bs[lk + 0][lr] = b4.x; Bs[lk + 1][lr] = b4.y; Bs[lk + 2][lr] = b4.z; Bs[lk + 3][lr] = b4.w;
        __syncthreads();
        #pragma unroll
        for (int kk = 0; kk < 16; ++kk) {
            float av[4], bv[4];
            #pragma unroll
            for (int i = 0; i < 4; ++i) av[i] = As[kk][ty * 4 + i];
            #pragma unroll
            for (int j = 0; j < 4; ++j) bv[j] = Bs[kk][tx * 4 + j];
            #pragma unroll
            for (int i = 0; i < 4; ++i)
            #pragma unroll
            for (int j = 0; j < 4; ++j) c[i][j] += av[i] * bv[j];
        }
    }
    #pragma unroll
    for (int i = 0; i < 4; ++i)
    #pragma unroll
    for (int j = 0; j < 4; ++j)
        hmat[(size_t)(n0 + ty * 4 + i) * 512 + m0 + tx * 4 + j] = c[i][j];
}

// ------- clustering (r14 proven): incremental Hopfield, h0 precomputed --------
#define CB 2
__device__ __forceinline__ float sgnf(float x) {
    return (x > 0.f) ? 1.f : ((x < 0.f) ? -1.f : 0.f);
}

__global__ __launch_bounds__(256) void clustering(const float* __restrict__ lat,
                                                  const float* __restrict__ hmat,
                                                  const float* __restrict__ w,
                                                  const float* __restrict__ rep,
                                                  float* __restrict__ out) {
    const int tid = threadIdx.x;
    const int row0 = blockIdx.x * CB;
    __shared__ float mins[CB][512];
    __shared__ float red[256];
    __shared__ float part_e[4][CB];
    __shared__ int part_c[4];
    __shared__ float min_e[CB];
    __shared__ int copyf[CB];
    __shared__ int donef[CB];
    __shared__ int cnt[CB];
    __shared__ int jidx[CB][512];
    __shared__ float jdel[CB][512];
    const int i0 = 2 * tid, i1 = 2 * tid + 1;
    const int wave = tid >> 6, lane = tid & 63;

    float sm10[CB], sm11[CB], sm20[CB], sm21[CB], h0[CB], h1[CB];
    #pragma unroll
    for (int r = 0; r < CB; ++r) {
        float a = tanhf(lat[(row0 + r) * 512 + i0]);
        float b = tanhf(lat[(row0 + r) * 512 + i1]);
        sm10[r] = a; sm11[r] = b;
        sm20[r] = a; sm21[r] = b;
        h0[r] = hmat[(size_t)(row0 + r) * 512 + i0];
        h1[r] = hmat[(size_t)(row0 + r) * 512 + i1];
    }
    if (tid < CB) { min_e[tid] = INFINITY; donef[tid] = 0; cnt[tid] = 0; }
    __syncthreads();

    for (int k = 1; k <= 512; ++k) {
        float sn0[CB], sn1[CB];
        int cy = (1 << CB) - 1;
        #pragma unroll
        for (int r = 0; r < CB; ++r) {
            int dn = donef[r];
            if (dn) {
                sn0[r] = sm10[r]; sn1[r] = sm11[r];
            } else {
                sn0[r] = fabsf(sm10[r]) * sgnf(h0[r]);
                sn1[r] = fabsf(sm11[r]) * sgnf(h1[r]);
                if (!(sn0[r] == sm20[r] && sn1[r] == sm21[r])) cy &= ~(1 << r);
                if (sn0[r] != sm10[r]) {
                    int p = atomicAdd(&cnt[r], 1);
                    jidx[r][p] = i0; jdel[r][p] = sn0[r] - sm10[r];
                }
                if (sn1[r] != sm11[r]) {
                    int p = atomicAdd(&cnt[r], 1);
                    jidx[r][p] = i1; jdel[r][p] = sn1[r] - sm11[r];
                }
            }
        }
        #pragma unroll
        for (int m = 32; m >= 1; m >>= 1) cy &= __shfl_xor(cy, m, 64);
        if (lane == 0) part_c[wave] = cy;
        __syncthreads();

        #pragma unroll
        for (int r = 0; r < CB; ++r) {
            const int c = cnt[r];
            #pragma unroll 4
            for (int t = 0; t < c; ++t) {
                const int j = jidx[r][t];
                const float d = jdel[r][t];
                const float2 wvv = *(const float2*)(w + (size_t)j * 512 + i0);
                h0[r] = fmaf(d, wvv.x, h0[r]);
                h1[r] = fmaf(d, wvv.y, h1[r]);
            }
        }
        float ep[CB];
        #pragma unroll
        for (int r = 0; r < CB; ++r) ep[r] = sn0[r] * h0[r] + sn1[r] * h1[r];
        #pragma unroll
        for (int m = 32; m >= 1; m >>= 1) {
            #pragma unroll
            for (int r = 0; r < CB; ++r) ep[r] += __shfl_xor(ep[r], m, 64);
        }
        if (lane == 0) {
            #pragma unroll
            for (int r = 0; r < CB; ++r) part_e[wave][r] = ep[r];
        }
        __syncthreads();

        if (tid < CB) {
            int r = tid;
            if (!donef[r]) {
                float e = -(part_e[0][r] + part_e[1][r] + part_e[2][r] + part_e[3][r]);
                int better = e < min_e[r];
                if (better) min_e[r] = e;
                copyf[r] = better;
                int fl = part_c[0] & part_c[1] & part_c[2] & part_c[3];
                int fixedp = (cnt[r] == 0);
                int cyc = (k >= 2) && ((fl >> r) & 1);
                if (fixedp || cyc) donef[r] = 1;
            } else {
                copyf[r] = 0;
            }
            cnt[r] = 0;
        }
        __syncthreads();

        int alldone = 1;
        #pragma unroll
        for (int r = 0; r < CB; ++r) {
            if (copyf[r]) { mins[r][i0] = sn0[r]; mins[r][i1] = sn1[r]; }
            alldone &= donef[r];
            sm20[r] = sm10[r]; sm21[r] = sm11[r];
            sm10[r] = sn0[r];  sm11[r] = sn1[r];
        }
        if (alldone) break;
    }
    __syncthreads();

    const int j = tid & 127, half = tid >> 7;
    for (int r = 0; r < CB; ++r) {
        const float4* rr = (const float4*)(rep + (size_t)j * 512 + half * 256);
        const float4* ms = (const float4*)(&mins[r][half * 256]);
        float p = 0.f;
        #pragma unroll 8
        for (int q = 0; q < 64; ++q) {
            float4 rv = rr[q], mv = ms[q];
            p += rv.x * mv.x + rv.y * mv.y + rv.z * mv.z + rv.w * mv.w;
        }
        red[tid] = p;
        __syncthreads();
        float v = 0.f;
        if (tid < 128) { v = fabsf(red[tid] + red[tid + 128]); red[tid] = v; }
        __syncthreads();
        for (int off = 64; off >= 1; off >>= 1) {
            if (tid < off) red[tid] = fmaxf(red[tid], red[tid + off]);
            __syncthreads();
        }
        float mx = red[0];
        __syncthreads();
        float ex = 0.f;
        if (tid < 128) { ex = expf(v - mx); red[tid] = ex; }
        __syncthreads();
        for (int off = 64; off >= 1; off >>= 1) {
            if (tid < off) red[tid] += red[tid + off];
            __syncthreads();
        }
        if (tid < 128) out[(size_t)(row0 + r) * 128 + tid] = ex / red[0];
        __syncthreads();
    }
}

extern "C" void kernel_launch(void* const* d_in, const int* in_sizes, int n_in,
                              void* d_out, int out_size, void* d_ws, size_t ws_size,
                              hipStream_t stream) {
    const float* image = (const float*)d_in[0];
    const float* limg  = (const float*)d_in[1];
    const float* c1w   = (const float*)d_in[2];
    const float* c1b   = (const float*)d_in[3];
    const float* c2w   = (const float*)d_in[4];
    const float* c2b   = (const float*)d_in[5];
    const float* f1w   = (const float*)d_in[6];
    const float* f1b   = (const float*)d_in[7];
    const float* fnw   = (const float*)d_in[8];
    const float* fnb   = (const float*)d_in[9];
    float* out = (float*)d_out;
    float* ws  = (float*)d_ws;

    unsigned short* o1b  = (unsigned short*)ws;        // 1152*12800 us = 29.5MB
    unsigned short* out2 = o1b + (size_t)NTOT * 12800; // 2*ASTR bf16
    float* lat  = (float*)(out2 + 2 * ASTR);           // 1024*512
    float* rep  = lat + (size_t)BATCH * 512;           // 128*512
    float* tT   = rep + (size_t)LABEL * 512;           // 512*128
    float* wmat = tT + (size_t)512 * 128;              // 512*512
    float* rho  = wmat + (size_t)512 * 512;            // 1 (+pad)
    unsigned short* Bw2   = (unsigned short*)(rho + 16);   // 2*BSTR bf16
    unsigned short* Bfrag = Bw2 + 2 * BSTR;                // 102,400 bf16
    float* hmat = (float*)(Bfrag + 102400);            // 1024*512 f32
    unsigned short* lat2 = (unsigned short*)(hmat + A2STR);  // 2*A2STR bf16
    unsigned short* fnw2 = lat2 + 2 * A2STR;           // 2*W2STR bf16
    float* logits = (float*)(fnw2 + 2 * W2STR);        // 1024*128 f32
    float* part = (float*)ws;                          // alias o1b (dead after conv2)

    const int prep_total = 102400 + 512 * 3136 + 128 * 512;
    hipLaunchKernelGGL(prep, dim3((prep_total + 255) / 256), dim3(256), 0, stream,
                       c2w, f1w, fnw, Bfrag, Bw2, fnw2);
    hipLaunchKernelGGL(conv1_pool, dim3(NTOT), dim3(256), 0, stream, image, limg, c1w, c1b, o1b);
    hipLaunchKernelGGL(conv2_mfma, dim3(NTOT), dim3(256), 0, stream, o1b, Bfrag, c2b, out2);
    hipLaunchKernelGGL(fc1_mfma, dim3(NTOT / 64, 512 / 64, 7), dim3(256), 0, stream,
                       out2, Bw2, part);
    hipLaunchKernelGGL(fc1_reduce, dim3(NTOT * 512 / 256), dim3(256), 0, stream,
                       part, f1b, lat, lat2, rep);
    hipLaunchKernelGGL(fcn_mfma, dim3(16, 2), dim3(256), 0, stream, lat2, fnw2, logits);
    hipLaunchKernelGGL(fcn_softmax2, dim3(BATCH), dim3(128), 0, stream, logits, fnb,
                       out + (size_t)BATCH * LABEL);
    hipLaunchKernelGGL(rho_kernel, dim3(1), dim3(256), 0, stream, rep, rho);
    hipLaunchKernelGGL(t_kernel, dim3(256), dim3(256), 0, stream, rep, rho, tT);
    hipLaunchKernelGGL(w_kernel, dim3(1024), dim3(256), 0, stream, tT, wmat);
    hipLaunchKernelGGL(hinit, dim3(BATCH / 64, 512 / 64), dim3(256), 0, stream, lat, wmat, hmat);
    hipLaunchKernelGGL(clustering, dim3(BATCH / CB), dim3(256), 0, stream,
                       lat, hmat, wmat, rep, out);
}

// Round 18
// 400.384 us; speedup vs baseline: 1.2671x; 1.0021x over previous
//
#include <hip/hip_runtime.h>
#include <hip/hip_bf16.h>
#include <math.h>

#define BATCH 1024
#define LABEL 128
#define LATENT 512
#define NTOT 1152  // 1024 + 128

typedef short short8 __attribute__((ext_vector_type(8)));
typedef float f32x16 __attribute__((ext_vector_type(16)));

__device__ __forceinline__ unsigned short f2bf(float f) {
    __hip_bfloat16 h = __float2bfloat16(f);
    return *(unsigned short*)&h;
}
__device__ __forceinline__ float bf2f(unsigned short u) {
    __hip_bfloat16 h; *(unsigned short*)&h = u;
    return __bfloat162float(h);
}

#define BSTR ((size_t)512 * 3136)
#define ASTR ((size_t)NTOT * 3136)
#define A2STR ((size_t)BATCH * 512)
#define W2STR ((size_t)LABEL * 512)

// conv1 output layout (per image): 2 bf16 planes of 6400 ushorts.
// Plane = 196 compact pixels (14x14) x 32ch, granule = 64B, slot-swizzled:
// off = p*32 + (((oc>>3) ^ (p>>1)) & 3)*8 + (oc&7).  Granules 196..199 zeroed.
//
// NUMERICS RULE (r15): w_kernel/t/rho keep r14-exact op order (Hopfield sign
// cascades). t_kernel may be re-laid-out (elementwise, no reduction).
// COVERAGE RULE (r16): conv1 must write all 196 pixels (xh loop).

// ------- conv1 v3 (r17 proven) ------------------------------------------------
__global__ __launch_bounds__(256) void conv1_pool(const float* __restrict__ image,
                                                  const float* __restrict__ limg,
                                                  const float* __restrict__ wt,
                                                  const float* __restrict__ bias,
                                                  unsigned short* __restrict__ o1b) {
    const int n = blockIdx.x;
    const float* in = (n < BATCH) ? (image + (size_t)n * 784)
                                  : (limg + (size_t)(n - BATCH) * 784);
    __shared__ float pin[32][32];
    __shared__ float wts[32 * 25];
    const int tid = threadIdx.x;
    unsigned short* ob = o1b + (size_t)n * 12800;
    for (int i = tid; i < 256; i += 256) {
        int pl_ = i >> 7, r = i & 127;
        ob[pl_ * 6400 + 6272 + r] = 0;
    }
    for (int idx = tid; idx < 32 * 32; idx += 256) ((float*)pin)[idx] = 0.f;
    __syncthreads();
    for (int idx = tid; idx < 784; idx += 256) {
        int y = idx / 28, x = idx % 28;
        pin[y + 2][x + 2] = in[idx];
    }
    for (int idx = tid; idx < 800; idx += 256) wts[idx] = wt[idx];
    __syncthreads();
    const int oc = tid & 31;
    float wk[25];
    #pragma unroll
    for (int k = 0; k < 25; ++k) wk[k] = wts[oc * 25 + k];
    const float b = bias[oc];
    const int slot_lo = (oc & 7);
    const int gq = oc >> 3;
    for (int it = 0; it < 2; ++it) {
        const int py = (tid >> 5) + it * 8;
        if (py >= 14) continue;
        #pragma unroll
        for (int xh = 0; xh < 2; ++xh) {
            const int acol = xh ? 12 : 0;
            const int off = xh ? 2 : 0;
            float a0[14], a1[14];
            #pragma unroll
            for (int c = 0; c < 14; ++c) { a0[c] = b; a1[c] = b; }
            #pragma unroll
            for (int t = 0; t < 6; ++t) {
                float row[20];
                const float4* rp = (const float4*)&pin[2 * py + t][acol];
                #pragma unroll
                for (int v = 0; v < 5; ++v) {
                    float4 f = rp[v];
                    row[4 * v] = f.x; row[4 * v + 1] = f.y;
                    row[4 * v + 2] = f.z; row[4 * v + 3] = f.w;
                }
                if (t < 5) {
                    #pragma unroll
                    for (int kx = 0; kx < 5; ++kx) {
                        float w0 = wk[t * 5 + kx];
                        #pragma unroll
                        for (int c = 0; c < 14; ++c)
                            a0[c] = fmaf(row[c + kx + off], w0, a0[c]);
                    }
                }
                if (t >= 1) {
                    #pragma unroll
                    for (int kx = 0; kx < 5; ++kx) {
                        float w1 = wk[(t - 1) * 5 + kx];
                        #pragma unroll
                        for (int c = 0; c < 14; ++c)
                            a1[c] = fmaf(row[c + kx + off], w1, a1[c]);
                    }
                }
            }
            #pragma unroll
            for (int px = 0; px < 7; ++px) {
                float v = fmaxf(fmaxf(a0[2 * px], a0[2 * px + 1]),
                                fmaxf(a1[2 * px], a1[2 * px + 1]));
                v = fmaxf(v, 0.f);
                unsigned short b1 = f2bf(v);
                unsigned short b2 = f2bf(v - bf2f(b1));
                int p = py * 14 + 7 * xh + px;
                int offo = p * 32 + (((gq ^ (p >> 1)) & 3) << 3) + slot_lo;
                ob[offo] = b1; ob[6400 + offo] = b2;
            }
        }
    }
}

// ------- merged prep (r17 proven) ---------------------------------------------
__global__ __launch_bounds__(256) void prep(const float* __restrict__ c2w,
                                            const float* __restrict__ f1w,
                                            const float* __restrict__ fnw,
                                            unsigned short* __restrict__ Bf,
                                            unsigned short* __restrict__ Bw2,
                                            unsigned short* __restrict__ Bn2) {
    int idx = blockIdx.x * 256 + threadIdx.x;
    if (idx < 102400) {
        int j = idx & 7, lane = (idx >> 3) & 63, ocT = (idx >> 9) & 1, s = idx >> 10;
        int q = lane >> 5, nn = lane & 31;
        int k = 16 * s + 8 * q + j;
        int tap = k >> 5, ic = k & 31;
        int oc = 32 * ocT + nn;
        float v = c2w[oc * 800 + ic * 25 + tap];
        unsigned short b1 = f2bf(v);
        unsigned short b2 = f2bf(v - bf2f(b1));
        size_t base = ((size_t)(s * 2 + ocT) * 2) * 512 + lane * 8 + j;
        Bf[base] = b1; Bf[base + 512] = b2;
        return;
    }
    int i2 = idx - 102400;
    if (i2 < 512 * 3136) {
        float v = f1w[i2];
        unsigned short b1 = f2bf(v);
        unsigned short b2 = f2bf(v - bf2f(b1));
        Bw2[i2] = b1; Bw2[BSTR + i2] = b2;
        return;
    }
    int i3 = i2 - 512 * 3136;
    if (i3 >= 128 * 512) return;
    float v = fnw[i3];
    unsigned short b1 = f2bf(v);
    unsigned short b2 = f2bf(v - bf2f(b1));
    Bn2[i3] = b1; Bn2[W2STR + i3] = b2;
}

// ------- conv2 via MFMA, v7 (r13 proven, unchanged) ---------------------------
__global__ __launch_bounds__(256) void conv2_mfma(const unsigned short* __restrict__ o1b,
                                                  const unsigned short* __restrict__ Bf,
                                                  const float* __restrict__ bias,
                                                  unsigned short* __restrict__ out2) {
    const int n = blockIdx.x;
    __shared__ __align__(16) unsigned short pl[12800];
    const int tid = threadIdx.x;
    const int lane = tid & 63, wv = tid >> 6;
    const int ocT = wv & 1, mh = wv >> 1;

    {
        const float4* src = (const float4*)(o1b + (size_t)n * 12800);
        float4* dst = (float4*)pl;
        for (int i = tid; i < 1600; i += 256) dst[i] = src[i];
    }
    __syncthreads();

    const int m_ = lane & 31, q = lane >> 5;
    int ym[4], xm[4], mm[4], tvv[4];
    #pragma unroll
    for (int tt = 0; tt < 4; ++tt) {
        int t = 4 * mh + tt;
        tvv[tt] = (t < 7);
        int m = 32 * t + m_;
        mm[tt] = m;
        ym[tt] = m / 14;
        xm[tt] = m - 14 * ym[tt];
    }
    f32x16 acc[4];
    {
        float bs = bias[32 * ocT + m_];
        #pragma unroll
        for (int tt = 0; tt < 4; ++tt)
        #pragma unroll
        for (int r = 0; r < 16; ++r) acc[tt][r] = bs;
    }

    for (int s = 0; s < 50; ++s) {
        const unsigned short* bp = Bf + ((size_t)(s * 2 + ocT) * 2) * 512 + lane * 8;
        short8 b1 = *(const short8*)(bp);
        short8 b2 = *(const short8*)(bp + 512);
        int kb = 16 * s + 8 * q;
        int tap = kb >> 5, ic0 = kb & 31, g = ic0 >> 3;
        int ky = (tap * 13) >> 6;
        int kx = tap - ky * 5;
        int iyk = ky - 2, ixk = kx - 2;
        int pq2 = iyk * 14 + ixk;
        short8 a1[4], a2[4];
        #pragma unroll
        for (int tt = 0; tt < 4; ++tt) {
            int iy = ym[tt] + iyk, ix = xm[tt] + ixk;
            int valid = tvv[tt] & ((unsigned)iy < 14u) & ((unsigned)ix < 14u);
            int cpt = valid ? (mm[tt] + pq2) : 196;
            int addr = cpt * 32 + (((g ^ (cpt >> 1)) & 3) << 3);
            a1[tt] = *(const short8*)(pl + addr);
            a2[tt] = *(const short8*)(pl + 6400 + addr);
        }
        #pragma unroll
        for (int tt = 0; tt < 4; ++tt)
            acc[tt] = __builtin_amdgcn_mfma_f32_32x32x16_bf16(a1[tt], b1, acc[tt], 0, 0, 0);
        #pragma unroll
        for (int tt = 0; tt < 4; ++tt)
            acc[tt] = __builtin_amdgcn_mfma_f32_32x32x16_bf16(a1[tt], b2, acc[tt], 0, 0, 0);
        #pragma unroll
        for (int tt = 0; tt < 4; ++tt)
            acc[tt] = __builtin_amdgcn_mfma_f32_32x32x16_bf16(a2[tt], b1, acc[tt], 0, 0, 0);
    }
    __syncthreads();

    float* hx = (float*)pl;
    {
        const int oc = 32 * ocT + m_;
        #pragma unroll
        for (int tt = 0; tt < 4; ++tt)
        #pragma unroll
        for (int e = 0; e < 8; ++e) {
            const int reg = 2 * e;
            const int r = (reg & 3) + 8 * (reg >> 2) + 4 * q;
            const int m = 32 * (4 * mh + tt) + r;
            if (m < 196) {
                float xm2 = fmaxf(acc[tt][reg], acc[tt][reg + 1]);
                int y = (m * 2341) >> 15;
                int px = (m - 14 * y) >> 1;
                hx[(y * 7 + px) * 65 + oc] = xm2;
            }
        }
    }
    __syncthreads();

    for (int idx = tid; idx < 3136; idx += 256) {
        int oc2 = (idx * 2675) >> 17;
        int p = idx - 49 * oc2;
        int py = (p * 9363) >> 16;
        int px = p - 7 * py;
        float v = fmaxf(hx[(2 * py * 7 + px) * 65 + oc2],
                        hx[((2 * py + 1) * 7 + px) * 65 + oc2]);
        v = fmaxf(v, 0.f);
        unsigned short b1 = f2bf(v);
        unsigned short b2 = f2bf(v - bf2f(b1));
        size_t o = (size_t)n * 3136 + idx;
        out2[o] = b1; out2[ASTR + o] = b2;
    }
}

// ------- fc1 via MFMA (r14 proven) --------------------------------------------
__global__ __launch_bounds__(256) void fc1_mfma(const unsigned short* __restrict__ A2,
                                                const unsigned short* __restrict__ B2,
                                                float* __restrict__ part) {
    __shared__ unsigned short As[2][2048];
    __shared__ unsigned short Bs[2][2048];
    const int tid = threadIdx.x;
    const int n0 = blockIdx.x * 64, m0 = blockIdx.y * 64;
    const int koff = blockIdx.z * 448;
    const int lr = tid >> 2, g = tid & 3;
    const int slot = (((g ^ (lr >> 1)) & 3) << 3);
    const int lane = tid & 63, wv = tid >> 6;
    const int nq = wv & 1, mq = wv >> 1;
    const int q = lane >> 5, l31 = lane & 31;
    const int rA = 32 * nq + l31, rB = 32 * mq + l31;
    f32x16 acc;
    #pragma unroll
    for (int r = 0; r < 16; ++r) acc[r] = 0.f;

    for (int bk = 0; bk < 448; bk += 32) {
        const size_t ka = (size_t)(koff + bk + (g << 3));
        short8 av[2], bv[2];
        #pragma unroll
        for (int p = 0; p < 2; ++p) {
            av[p] = *(const short8*)(A2 + p * ASTR + (size_t)(n0 + lr) * 3136 + ka);
            bv[p] = *(const short8*)(B2 + p * BSTR + (size_t)(m0 + lr) * 3136 + ka);
        }
        __syncthreads();
        #pragma unroll
        for (int p = 0; p < 2; ++p) {
            *(short8*)&As[p][(lr << 5) + slot] = av[p];
            *(short8*)&Bs[p][(lr << 5) + slot] = bv[p];
        }
        __syncthreads();
        #pragma unroll
        for (int s2 = 0; s2 < 32; s2 += 16) {
            const int gg = (s2 + (q << 3)) >> 3;
            const int sa = (((gg ^ (rA >> 1)) & 3) << 3);
            const int sb = (((gg ^ (rB >> 1)) & 3) << 3);
            short8 a1 = *(const short8*)&As[0][(rA << 5) + sa];
            short8 a2 = *(const short8*)&As[1][(rA << 5) + sa];
            short8 b1 = *(const short8*)&Bs[0][(rB << 5) + sb];
            short8 b2 = *(const short8*)&Bs[1][(rB << 5) + sb];
            acc = __builtin_amdgcn_mfma_f32_32x32x16_bf16(a1, b1, acc, 0, 0, 0);
            acc = __builtin_amdgcn_mfma_f32_32x32x16_bf16(a1, b2, acc, 0, 0, 0);
            acc = __builtin_amdgcn_mfma_f32_32x32x16_bf16(a2, b1, acc, 0, 0, 0);
        }
    }
    float* pb = part + (size_t)blockIdx.z * NTOT * 512;
    #pragma unroll
    for (int reg = 0; reg < 16; ++reg) {
        int nn = n0 + 32 * nq + (reg & 3) + 8 * (reg >> 2) + 4 * q;
        int mmo = m0 + 32 * mq + l31;
        pb[(size_t)nn * 512 + mmo] = acc[reg];
    }
}

__global__ __launch_bounds__(256) void fc1_reduce(const float* __restrict__ part,
                                                  const float* __restrict__ bias,
                                                  float* __restrict__ lat,
                                                  unsigned short* __restrict__ lat2,
                                                  float* __restrict__ rep) {
    int idx = blockIdx.x * 256 + threadIdx.x;
    int m = idx & 511;
    float v = bias[m];
    #pragma unroll
    for (int kz = 0; kz < 7; ++kz) v += part[(size_t)kz * NTOT * 512 + idx];
    if (idx < BATCH * 512) {
        lat[idx] = v;
        unsigned short b1 = f2bf(v);
        lat2[idx] = b1;
        lat2[A2STR + idx] = f2bf(v - bf2f(b1));
    } else {
        rep[idx - BATCH * 512] = tanhf(v);
    }
}

// ------- fcn logits via MFMA (r17 proven) -------------------------------------
__global__ __launch_bounds__(256) void fcn_mfma(const unsigned short* __restrict__ A2,
                                                const unsigned short* __restrict__ B2,
                                                float* __restrict__ logits) {
    __shared__ unsigned short As[2][2048];
    __shared__ unsigned short Bs[2][2048];
    const int tid = threadIdx.x;
    const int n0 = blockIdx.x * 64, m0 = blockIdx.y * 64;
    const int lr = tid >> 2, g = tid & 3;
    const int slot = (((g ^ (lr >> 1)) & 3) << 3);
    const int lane = tid & 63, wv = tid >> 6;
    const int nq = wv & 1, mq = wv >> 1;
    const int q = lane >> 5, l31 = lane & 31;
    const int rA = 32 * nq + l31, rB = 32 * mq + l31;
    f32x16 acc;
    #pragma unroll
    for (int r = 0; r < 16; ++r) acc[r] = 0.f;

    for (int bk = 0; bk < 512; bk += 32) {
        const size_t ka = (size_t)(bk + (g << 3));
        short8 av[2], bv[2];
        #pragma unroll
        for (int p = 0; p < 2; ++p) {
            av[p] = *(const short8*)(A2 + p * A2STR + (size_t)(n0 + lr) * 512 + ka);
            bv[p] = *(const short8*)(B2 + p * W2STR + (size_t)(m0 + lr) * 512 + ka);
        }
        __syncthreads();
        #pragma unroll
        for (int p = 0; p < 2; ++p) {
            *(short8*)&As[p][(lr << 5) + slot] = av[p];
            *(short8*)&Bs[p][(lr << 5) + slot] = bv[p];
        }
        __syncthreads();
        #pragma unroll
        for (int s2 = 0; s2 < 32; s2 += 16) {
            const int gg = (s2 + (q << 3)) >> 3;
            const int sa = (((gg ^ (rA >> 1)) & 3) << 3);
            const int sb = (((gg ^ (rB >> 1)) & 3) << 3);
            short8 a1 = *(const short8*)&As[0][(rA << 5) + sa];
            short8 a2 = *(const short8*)&As[1][(rA << 5) + sa];
            short8 b1 = *(const short8*)&Bs[0][(rB << 5) + sb];
            short8 b2 = *(const short8*)&Bs[1][(rB << 5) + sb];
            acc = __builtin_amdgcn_mfma_f32_32x32x16_bf16(a1, b1, acc, 0, 0, 0);
            acc = __builtin_amdgcn_mfma_f32_32x32x16_bf16(a1, b2, acc, 0, 0, 0);
            acc = __builtin_amdgcn_mfma_f32_32x32x16_bf16(a2, b1, acc, 0, 0, 0);
        }
    }
    #pragma unroll
    for (int reg = 0; reg < 16; ++reg) {
        int nn = n0 + 32 * nq + (reg & 3) + 8 * (reg >> 2) + 4 * q;
        int mmo = m0 + 32 * mq + l31;
        logits[(size_t)nn * 128 + mmo] = acc[reg];
    }
}

__global__ __launch_bounds__(128) void fcn_softmax2(const float* __restrict__ logits,
                                                    const float* __restrict__ fb,
                                                    float* __restrict__ out) {
    const int b = blockIdx.x;
    const int j = threadIdx.x;
    __shared__ float red[128];
    float acc = logits[(size_t)b * 128 + j] + fb[j];
    red[j] = acc;
    __syncthreads();
    for (int off = 64; off >= 1; off >>= 1) {
        if (j < off) red[j] = fmaxf(red[j], red[j + off]);
        __syncthreads();
    }
    float mx = red[0];
    __syncthreads();
    float ex = expf(acc - mx);
    red[j] = ex;
    __syncthreads();
    for (int off = 64; off >= 1; off >>= 1) {
        if (j < off) red[j] += red[j + off];
        __syncthreads();
    }
    out[(size_t)b * 128 + j] = ex / red[0];
}

// ------- rho (r14-exact, numerics load-bearing) -------------------------------
__global__ __launch_bounds__(256) void rho_kernel(const float* __restrict__ rep,
                                                  float* __restrict__ rho) {
    __shared__ float red[256];
    const int tid = threadIdx.x;
    float s = 0.f;
    for (int i = tid; i < LABEL * LATENT; i += 256) s += rep[i];
    red[tid] = s;
    __syncthreads();
    for (int off = 128; off >= 1; off >>= 1) {
        if (tid < off) red[tid] += red[tid + off];
        __syncthreads();
    }
    if (tid == 0) rho[0] = red[0] / (float)(LABEL * LATENT);
}

// ------- t v2: LDS tile transpose (elementwise -> bit-exact by construction) --
// tT[i][k] = rep[k][i] - rho.  Tile 64x64, grid (8,2): coalesced read + write.
__global__ __launch_bounds__(256) void t_kernel(const float* __restrict__ rep,
                                                const float* __restrict__ rho,
                                                float* __restrict__ tT) {
    __shared__ float tile[64][65];
    const int tid = threadIdx.x;
    const int i0 = blockIdx.x * 64, k0 = blockIdx.y * 64;
    const int tx = tid & 63, ty4 = tid >> 6;
    const float r0 = rho[0];
    #pragma unroll
    for (int rr = 0; rr < 16; ++rr) {
        int kk = ty4 * 16 + rr;          // 0..63
        tile[kk][tx] = rep[(size_t)(k0 + kk) * 512 + i0 + tx];
    }
    __syncthreads();
    #pragma unroll
    for (int rr = 0; rr < 16; ++rr) {
        int ii = ty4 * 16 + rr;
        tT[(size_t)(i0 + ii) * 128 + k0 + tx] = tile[tx][ii] - r0;
    }
}

// ------- w_kernel: r14-EXACT (summation order load-bearing) -------------------
__global__ __launch_bounds__(256) void w_kernel(const float* __restrict__ tT,
                                                float* __restrict__ w) {
    int idx = blockIdx.x * 256 + threadIdx.x;
    int i = idx >> 9, j = idx & 511;
    const float4* a = (const float4*)(tT + i * 128);
    const float4* b = (const float4*)(tT + j * 128);
    float acc = 0.f;
    #pragma unroll 8
    for (int q = 0; q < 32; ++q) {
        float4 av = a[q], bv = b[q];
        acc += av.x * bv.x + av.y * bv.y + av.z * bv.z + av.w * bv.w;
    }
    w[idx] = (i == j) ? 0.f : acc * (1.f / 128.f);
}

// ------- hinit (r14 proven) ---------------------------------------------------
__global__ __launch_bounds__(256) void hinit(const float* __restrict__ lat,
                                             const float* __restrict__ w,
                                             float* __restrict__ hmat) {
    __shared__ float As[16][68];
    __shared__ float Bs[16][68];
    const int tid = threadIdx.x;
    const int n0 = blockIdx.x * 64, m0 = blockIdx.y * 64;
    const int lr = tid >> 2;
    const int lk = (tid & 3) * 4;
    const int ty = tid >> 4, tx = tid & 15;
    float c[4][4] = {};
    for (int k0 = 0; k0 < 512; k0 += 16) {
        float4 a4 = *(const float4*)(lat + (size_t)(n0 + lr) * 512 + k0 + lk);
        float4 b4 = *(const float4*)(w + (size_t)(m0 + lr) * 512 + k0 + lk);
        a4.x = tanhf(a4.x); a4.y = tanhf(a4.y); a4.z = tanhf(a4.z); a4.w = tanhf(a4.w);
        __syncthreads();
        As[lk + 0][lr] = a4.x; As[lk + 1][lr] = a4.y; As[lk + 2][lr] = a4.z; As[lk + 3][lr] = a4.w;
        Bs[lk + 0][lr] = b4.x; Bs[lk + 1][lr] = b4.y; Bs[lk + 2][lr] = b4.z; Bs[lk + 3][lr] = b4.w;
        __syncthreads();
        #pragma unroll
        for (int kk = 0; kk < 16; ++kk) {
            float av[4], bv[4];
            #pragma unroll
            for (int i = 0; i < 4; ++i) av[i] = As[kk][ty * 4 + i];
            #pragma unroll
            for (int j = 0; j < 4; ++j) bv[j] = Bs[kk][tx * 4 + j];
            #pragma unroll
            for (int i = 0; i < 4; ++i)
            #pragma unroll
            for (int j = 0; j < 4; ++j) c[i][j] += av[i] * bv[j];
        }
    }
    #pragma unroll
    for (int i = 0; i < 4; ++i)
    #pragma unroll
    for (int j = 0; j < 4; ++j)
        hmat[(size_t)(n0 + ty * 4 + i) * 512 + m0 + tx * 4 + j] = c[i][j];
}

// ------- clustering v3: CB=1 (1024 blocks, 4/CU) + unroll-8 flip loads --------
__device__ __forceinline__ float sgnf(float x) {
    return (x > 0.f) ? 1.f : ((x < 0.f) ? -1.f : 0.f);
}

__global__ __launch_bounds__(256) void clustering(const float* __restrict__ lat,
                                                  const float* __restrict__ hmat,
                                                  const float* __restrict__ w,
                                                  const float* __restrict__ rep,
                                                  float* __restrict__ out) {
    const int tid = threadIdx.x;
    const int row = blockIdx.x;
    __shared__ float mins[512];
    __shared__ float red[256];
    __shared__ float part_e[4];
    __shared__ int part_c[4];
    __shared__ float min_e_s;
    __shared__ int copyf_s;
    __shared__ int donef_s;
    __shared__ int cnt_s;
    __shared__ int jidx[512];
    __shared__ float jdel[512];
    const int i0 = 2 * tid, i1 = 2 * tid + 1;
    const int wave = tid >> 6, lane = tid & 63;

    float sm10, sm11, sm20, sm21, h0, h1;
    {
        sm10 = tanhf(lat[(size_t)row * 512 + i0]);
        sm11 = tanhf(lat[(size_t)row * 512 + i1]);
        sm20 = sm10; sm21 = sm11;
        h0 = hmat[(size_t)row * 512 + i0];
        h1 = hmat[(size_t)row * 512 + i1];
    }
    if (tid == 0) { min_e_s = INFINITY; donef_s = 0; cnt_s = 0; }
    __syncthreads();

    for (int k = 1; k <= 512; ++k) {
        float sn0 = fabsf(sm10) * sgnf(h0);
        float sn1 = fabsf(sm11) * sgnf(h1);
        int cy = (sn0 == sm20 && sn1 == sm21) ? 1 : 0;
        if (sn0 != sm10) {
            int p = atomicAdd(&cnt_s, 1);
            jidx[p] = i0; jdel[p] = sn0 - sm10;
        }
        if (sn1 != sm11) {
            int p = atomicAdd(&cnt_s, 1);
            jidx[p] = i1; jdel[p] = sn1 - sm11;
        }
        #pragma unroll
        for (int m = 32; m >= 1; m >>= 1) cy &= __shfl_xor(cy, m, 64);
        if (lane == 0) part_c[wave] = cy;
        __syncthreads();   // flip list complete

        // h += W * delta over flipped columns (coalesced row reads, unroll 8)
        {
            const int c = cnt_s;
            #pragma unroll 8
            for (int t = 0; t < c; ++t) {
                const int j = jidx[t];
                const float d = jdel[t];
                const float2 wvv = *(const float2*)(w + (size_t)j * 512 + i0);
                h0 = fmaf(d, wvv.x, h0);
                h1 = fmaf(d, wvv.y, h1);
            }
        }
        float ep = sn0 * h0 + sn1 * h1;
        #pragma unroll
        for (int m = 32; m >= 1; m >>= 1) ep += __shfl_xor(ep, m, 64);
        if (lane == 0) part_e[wave] = ep;
        __syncthreads();

        if (tid == 0) {
            float e = -(part_e[0] + part_e[1] + part_e[2] + part_e[3]);
            int better = e < min_e_s;
            if (better) min_e_s = e;
            copyf_s = better;
            int fl = part_c[0] & part_c[1] & part_c[2] & part_c[3];
            int fixedp = (cnt_s == 0);
            int cyc = (k >= 2) && fl;
            if (fixedp || cyc) donef_s = 1;
            cnt_s = 0;
        }
        __syncthreads();

        if (copyf_s) { mins[i0] = sn0; mins[i1] = sn1; }
        sm20 = sm10; sm21 = sm11;
        sm10 = sn0;  sm11 = sn1;
        if (donef_s) break;
    }
    __syncthreads();

    // out[row] = softmax_j(|mins . rep_j|)
    const int j = tid & 127, half = tid >> 7;
    {
        const float4* rr = (const float4*)(rep + (size_t)j * 512 + half * 256);
        const float4* ms = (const float4*)(&mins[half * 256]);
        float p = 0.f;
        #pragma unroll 8
        for (int q = 0; q < 64; ++q) {
            float4 rv = rr[q], mv = ms[q];
            p += rv.x * mv.x + rv.y * mv.y + rv.z * mv.z + rv.w * mv.w;
        }
        red[tid] = p;
        __syncthreads();
        float v = 0.f;
        if (tid < 128) { v = fabsf(red[tid] + red[tid + 128]); red[tid] = v; }
        __syncthreads();
        for (int off = 64; off >= 1; off >>= 1) {
            if (tid < off) red[tid] = fmaxf(red[tid], red[tid + off]);
            __syncthreads();
        }
        float mx = red[0];
        __syncthreads();
        float ex = 0.f;
        if (tid < 128) { ex = expf(v - mx); red[tid] = ex; }
        __syncthreads();
        for (int off = 64; off >= 1; off >>= 1) {
            if (tid < off) red[tid] += red[tid + off];
            __syncthreads();
        }
        if (tid < 128) out[(size_t)row * 128 + tid] = ex / red[0];
    }
}

extern "C" void kernel_launch(void* const* d_in, const int* in_sizes, int n_in,
                              void* d_out, int out_size, void* d_ws, size_t ws_size,
                              hipStream_t stream) {
    const float* image = (const float*)d_in[0];
    const float* limg  = (const float*)d_in[1];
    const float* c1w   = (const float*)d_in[2];
    const float* c1b   = (const float*)d_in[3];
    const float* c2w   = (const float*)d_in[4];
    const float* c2b   = (const float*)d_in[5];
    const float* f1w   = (const float*)d_in[6];
    const float* f1b   = (const float*)d_in[7];
    const float* fnw   = (const float*)d_in[8];
    const float* fnb   = (const float*)d_in[9];
    float* out = (float*)d_out;
    float* ws  = (float*)d_ws;

    unsigned short* o1b  = (unsigned short*)ws;        // 1152*12800 us
    unsigned short* out2 = o1b + (size_t)NTOT * 12800; // 2*ASTR bf16
    float* lat  = (float*)(out2 + 2 * ASTR);           // 1024*512
    float* rep  = lat + (size_t)BATCH * 512;           // 128*512
    float* tT   = rep + (size_t)LABEL * 512;           // 512*128
    float* wmat = tT + (size_t)512 * 128;              // 512*512
    float* rho  = wmat + (size_t)512 * 512;            // 1 (+pad)
    unsigned short* Bw2   = (unsigned short*)(rho + 16);   // 2*BSTR bf16
    unsigned short* Bfrag = Bw2 + 2 * BSTR;                // 102,400 bf16
    float* hmat = (float*)(Bfrag + 102400);            // 1024*512 f32
    unsigned short* lat2 = (unsigned short*)(hmat + A2STR);  // 2*A2STR bf16
    unsigned short* fnw2 = lat2 + 2 * A2STR;           // 2*W2STR bf16
    float* logits = (float*)(fnw2 + 2 * W2STR);        // 1024*128 f32
    float* part = (float*)ws;                          // alias o1b (dead after conv2)

    const int prep_total = 102400 + 512 * 3136 + 128 * 512;
    hipLaunchKernelGGL(prep, dim3((prep_total + 255) / 256), dim3(256), 0, stream,
                       c2w, f1w, fnw, Bfrag, Bw2, fnw2);
    hipLaunchKernelGGL(conv1_pool, dim3(NTOT), dim3(256), 0, stream, image, limg, c1w, c1b, o1b);
    hipLaunchKernelGGL(conv2_mfma, dim3(NTOT), dim3(256), 0, stream, o1b, Bfrag, c2b, out2);
    hipLaunchKernelGGL(fc1_mfma, dim3(NTOT / 64, 512 / 64, 7), dim3(256), 0, stream,
                       out2, Bw2, part);
    hipLaunchKernelGGL(fc1_reduce, dim3(NTOT * 512 / 256), dim3(256), 0, stream,
                       part, f1b, lat, lat2, rep);
    hipLaunchKernelGGL(fcn_mfma, dim3(16, 2), dim3(256), 0, stream, lat2, fnw2, logits);
    hipLaunchKernelGGL(fcn_softmax2, dim3(BATCH), dim3(128), 0, stream, logits, fnb,
                       out + (size_t)BATCH * LABEL);
    hipLaunchKernelGGL(rho_kernel, dim3(1), dim3(256), 0, stream, rep, rho);
    hipLaunchKernelGGL(t_kernel, dim3(8, 2), dim3(256), 0, stream, rep, rho, tT);
    hipLaunchKernelGGL(w_kernel, dim3(1024), dim3(256), 0, stream, tT, wmat);
    hipLaunchKernelGGL(hinit, dim3(BATCH / 64, 512 / 64), dim3(256), 0, stream, lat, wmat, hmat);
    hipLaunchKernelGGL(clustering, dim3(BATCH), dim3(256), 0, stream,
                       lat, hmat, wmat, rep, out);
}